// Round 1
// baseline (4005.021 us; speedup 1.0000x reference)
//
#include <hip/hip_runtime.h>
#include <math.h>

#define D 128
#define BM 64
#define BK 16

// ---------------- scatter: S[w,v,:] += x[u,:] ----------------
// 32 lanes per edge, each lane handles 4 consecutive floats (float4 of x).
__global__ __launch_bounds__(256) void scatter_kernel(
    const float* __restrict__ x,
    const int* __restrict__ u,
    const int* __restrict__ v,
    const int* __restrict__ widx,
    float* __restrict__ S,
    long long E, long long N, int wFilter) {
  long long t = (long long)blockIdx.x * blockDim.x + threadIdx.x;
  long long e = t >> 5;
  int lane = (int)(t & 31);
  if (e >= E) return;
  int w = widx[e];
  if (wFilter >= 0 && w != wFilter) return;
  int uu = u[e];
  int vv = v[e];
  const float4* xs = (const float4*)(x + (long long)uu * D);
  float4 val = xs[lane];
  long long base;
  if (wFilter >= 0) base = (long long)vv * D;
  else              base = ((long long)w * N + (long long)vv) * D;
  float* dst = S + base + (long long)lane * 4;
  atomicAdd(dst + 0, val.x);
  atomicAdd(dst + 1, val.y);
  atomicAdd(dst + 2, val.z);
  atomicAdd(dst + 3, val.w);
}

// ---------------- grouped GEMM: out[v,i] (+)= sum_w sum_j S[w,v,j]*W[w,i,j] ----
// Block: 256 threads, tile BM=64 rows x 128 cols, each thread 4x8 outputs.
// W is transposed into LDS during staging (Wl[j][i]); S staged as Sl[v][j].
__global__ __launch_bounds__(256) void gemm_kernel(
    const float* __restrict__ S,   // base for w index wi=0 of this call
    const float* __restrict__ W,   // full W tensor [NW][D][D]
    float* __restrict__ out,
    long long N, int wOff, int wCount, long long sStrideW,
    int accumulate, int do_tanh) {
  __shared__ float Wl[BK][D + 4];       // padded: 132 floats/row (16B-aligned rows)
  __shared__ float Sl[BM][BK + 4];      // padded: 20 floats/row (16B-aligned rows)

  int tid = threadIdx.x;
  long long v0 = (long long)blockIdx.x * BM;
  int tx = tid & 15;        // column group: cols tx*8 .. tx*8+7
  int ty = tid >> 4;        // row group:  rows ty*4 .. ty*4+3

  float acc[4][8];
  #pragma unroll
  for (int r = 0; r < 4; ++r)
    #pragma unroll
    for (int c = 0; c < 8; ++c) acc[r][c] = 0.f;

  for (int wi = 0; wi < wCount; ++wi) {
    const float* Wb = W + (long long)(wOff + wi) * D * D;
    const float* Sb = S + (long long)wi * sStrideW;
    for (int jb = 0; jb < D; jb += BK) {
      // stage W chunk, transposed: Wl[jj][i] = Wb[i*D + jb + jj]
      {
        int i = tid >> 2;          // 0..63
        int g = tid & 3;           // j-group of 4
        #pragma unroll
        for (int rep = 0; rep < 2; ++rep) {
          float4 wv = *(const float4*)(Wb + (long long)(i + rep * 64) * D + jb + g * 4);
          Wl[g * 4 + 0][i + rep * 64] = wv.x;
          Wl[g * 4 + 1][i + rep * 64] = wv.y;
          Wl[g * 4 + 2][i + rep * 64] = wv.z;
          Wl[g * 4 + 3][i + rep * 64] = wv.w;
        }
      }
      // stage S chunk: Sl[vl][jj]
      {
        int vl = tid >> 2;         // 0..63
        int g = tid & 3;
        long long vv = v0 + vl;
        float4 sv = make_float4(0.f, 0.f, 0.f, 0.f);
        if (vv < N) sv = *(const float4*)(Sb + vv * D + jb + g * 4);
        *(float4*)&Sl[vl][g * 4] = sv;
      }
      __syncthreads();
      #pragma unroll
      for (int kk = 0; kk < BK; ++kk) {
        float ss[4];
        #pragma unroll
        for (int r = 0; r < 4; ++r) ss[r] = Sl[ty * 4 + r][kk];
        float4 wa = *(const float4*)&Wl[kk][tx * 8];
        float4 wb = *(const float4*)&Wl[kk][tx * 8 + 4];
        float wv[8] = {wa.x, wa.y, wa.z, wa.w, wb.x, wb.y, wb.z, wb.w};
        #pragma unroll
        for (int r = 0; r < 4; ++r)
          #pragma unroll
          for (int c = 0; c < 8; ++c)
            acc[r][c] += ss[r] * wv[c];
      }
      __syncthreads();
    }
  }

  // epilogue
  #pragma unroll
  for (int r = 0; r < 4; ++r) {
    long long vv = v0 + ty * 4 + r;
    if (vv >= N) continue;
    float* op = out + vv * D + tx * 8;
    float vals[8];
    #pragma unroll
    for (int c = 0; c < 8; ++c) vals[c] = acc[r][c];
    if (accumulate) {
      #pragma unroll
      for (int c = 0; c < 8; ++c) vals[c] += op[c];
    }
    if (do_tanh) {
      #pragma unroll
      for (int c = 0; c < 8; ++c) vals[c] = tanhf(vals[c]);
    }
    *(float4*)(op + 0) = make_float4(vals[0], vals[1], vals[2], vals[3]);
    *(float4*)(op + 4) = make_float4(vals[4], vals[5], vals[6], vals[7]);
  }
}

extern "C" void kernel_launch(void* const* d_in, const int* in_sizes, int n_in,
                              void* d_out, int out_size, void* d_ws, size_t ws_size,
                              hipStream_t stream) {
  const float* x    = (const float*)d_in[0];
  const float* W    = (const float*)d_in[1];
  const int*   u    = (const int*)d_in[2];
  const int*   v    = (const int*)d_in[3];
  const int*   widx = (const int*)d_in[4];

  long long N  = (long long)in_sizes[0] / D;
  int       NW = in_sizes[1] / (D * D);
  long long E  = (long long)in_sizes[2];
  float* out = (float*)d_out;

  size_t needFull = (size_t)NW * (size_t)N * D * sizeof(float);
  size_t needOne  = (size_t)N * D * sizeof(float);

  dim3 blk(256);
  long long scatterThreads = E * 32;
  int scatterGrid = (int)((scatterThreads + 255) / 256);
  int gemmGrid = (int)((N + BM - 1) / BM);

  if (ws_size >= needFull) {
    float* S = (float*)d_ws;
    hipMemsetAsync(S, 0, needFull, stream);
    scatter_kernel<<<scatterGrid, blk, 0, stream>>>(x, u, v, widx, S, E, N, -1);
    gemm_kernel<<<gemmGrid, blk, 0, stream>>>(S, W, out, N, 0, NW,
                                              (long long)N * D, 0, 1);
  } else if (ws_size >= needOne) {
    float* S = (float*)d_ws;
    for (int w = 0; w < NW; ++w) {
      hipMemsetAsync(S, 0, needOne, stream);
      scatter_kernel<<<scatterGrid, blk, 0, stream>>>(x, u, v, widx, S, E, N, w);
      gemm_kernel<<<gemmGrid, blk, 0, stream>>>(S, W, out, N, w, 1, 0,
                                                (w > 0) ? 1 : 0,
                                                (w == NW - 1) ? 1 : 0);
    }
  }
  // (ws_size smaller than one S plane is not expected for this problem)
}

// Round 2
// 2072.129 us; speedup vs baseline: 1.9328x; 1.9328x over previous
//
#include <hip/hip_runtime.h>
#include <math.h>

#define D 128
#define BMT 64            // v-tile rows
#define PADC 132          // padded LDS row (132 floats)

// ---------- Phase A2: histogram of edges into (w, vtile) buckets ----------
// counters padded to one cacheline (16 ints) each to cut atomic line contention
__global__ __launch_bounds__(256) void hist_kernel(
    const int* __restrict__ v, const int* __restrict__ widx,
    int* __restrict__ cntPad, long long E, int nTiles) {
  long long e = (long long)blockIdx.x * blockDim.x + threadIdx.x;
  if (e >= E) return;
  int b = widx[e] * nTiles + (v[e] >> 6);
  atomicAdd(&cntPad[(long long)b * 16], 1);
}

// ---------- Phase A3: exclusive scan over NB buckets (single block) ----------
__global__ __launch_bounds__(1024) void scan_kernel(
    const int* __restrict__ cntPad, int* __restrict__ starts,
    int* __restrict__ cursorPad, int NB) {
  __shared__ int part[1024];
  int tid = threadIdx.x;
  int per = (NB + 1023) / 1024;      // <= 16 assumed
  int base = tid * per;
  int local[16];
  int sum = 0;
  for (int i = 0; i < per; ++i) {
    int idx = base + i;
    int c = (idx < NB) ? cntPad[(long long)idx * 16] : 0;
    local[i] = sum;
    sum += c;
  }
  part[tid] = sum;
  __syncthreads();
  for (int off = 1; off < 1024; off <<= 1) {
    int val = (tid >= off) ? part[tid - off] : 0;
    __syncthreads();
    part[tid] += val;
    __syncthreads();
  }
  int excl = (tid == 0) ? 0 : part[tid - 1];
  for (int i = 0; i < per; ++i) {
    int idx = base + i;
    if (idx < NB) {
      int s = excl + local[i];
      starts[idx] = s;
      cursorPad[(long long)idx * 16] = s;
    }
  }
  if (tid == 1023) starts[NB] = excl + sum;
}

// ---------- Phase A4: scatter packed edge records into bucket order ----------
// record: u (24 bits) | vlow (6 bits, v & 63) << 24
__global__ __launch_bounds__(256) void scatter_ids_kernel(
    const int* __restrict__ u, const int* __restrict__ v,
    const int* __restrict__ widx, int* __restrict__ cursorPad,
    unsigned* __restrict__ sorted, long long E, int nTiles) {
  long long e = (long long)blockIdx.x * blockDim.x + threadIdx.x;
  if (e >= E) return;
  int vv = v[e];
  int b = widx[e] * nTiles + (vv >> 6);
  int pos = atomicAdd(&cursorPad[(long long)b * 16], 1);
  sorted[pos] = (unsigned)u[e] | ((unsigned)(vv & 63) << 24);
}

// ---------- Phase B: fused per-tile aggregate (LDS) + grouped GEMM + tanh ----
__global__ __launch_bounds__(256) void fused_kernel(
    const float* __restrict__ x, const float* __restrict__ W,
    const int* __restrict__ starts, const unsigned* __restrict__ sorted,
    float* __restrict__ out, long long N, int nTiles, int NW) {
  __shared__ float Stile[BMT][PADC];   // 64 x 132 f32 = 33.8 KB
  __shared__ float Wl[16][PADC];       // 16 x 132 f32 = 8.4 KB

  int tid = threadIdx.x;
  int t = blockIdx.x;
  long long v0 = (long long)t * BMT;
  int tx = tid & 15;        // output cols tx*8 .. +7
  int ty = tid >> 4;        // output rows ty*4 .. +3
  int sub = tid >> 5;       // 0..7 : edge slot within block
  int lane = tid & 31;

  float acc[4][8];
  #pragma unroll
  for (int r = 0; r < 4; ++r)
    #pragma unroll
    for (int c = 0; c < 8; ++c) acc[r][c] = 0.f;

  for (int w = 0; w < NW; ++w) {
    // zero S tile (including pad)
    {
      float4* sz = (float4*)&Stile[0][0];
      const int n4 = BMT * PADC / 4;   // 2112
      for (int i = tid; i < n4; i += 256) sz[i] = make_float4(0.f, 0.f, 0.f, 0.f);
    }
    __syncthreads();

    // aggregate edges of bucket (w, t): 8 edges in flight, 32 lanes each.
    // stride-1 lane mapping => each 32-lane group covers all 32 LDS banks
    // (conflict-free ds_add), and each round's global gather is a coalesced
    // 128B segment.
    {
      int b = w * nTiles + t;
      int s0 = starts[b];
      int s1 = starts[b + 1];
      for (int i = s0 + sub; i < s1; i += 8) {
        unsigned rec = sorted[i];
        int uu = (int)(rec & 0xFFFFFF);
        int vl = (int)(rec >> 24);
        const float* xs = x + (long long)uu * D;
        #pragma unroll
        for (int k = 0; k < 4; ++k) {
          float xv = xs[k * 32 + lane];
          atomicAdd(&Stile[vl][k * 32 + lane], xv);
        }
      }
    }
    __syncthreads();

    // GEMM: acc[r][c] += sum_j Stile[row][j] * W[w][col][j]
    const float* Wb = W + (long long)w * D * D;
    for (int jb = 0; jb < D; jb += 16) {
      // stage W chunk transposed: Wl[jj][i] = Wb[i*D + jb + jj]
      {
        int i = tid >> 2;
        int g = tid & 3;
        #pragma unroll
        for (int rep = 0; rep < 2; ++rep) {
          float4 wv = *(const float4*)(Wb + (long long)(i + rep * 64) * D + jb + g * 4);
          Wl[g * 4 + 0][i + rep * 64] = wv.x;
          Wl[g * 4 + 1][i + rep * 64] = wv.y;
          Wl[g * 4 + 2][i + rep * 64] = wv.z;
          Wl[g * 4 + 3][i + rep * 64] = wv.w;
        }
      }
      __syncthreads();
      #pragma unroll
      for (int kk = 0; kk < 16; ++kk) {
        float ss[4];
        #pragma unroll
        for (int r = 0; r < 4; ++r) ss[r] = Stile[ty * 4 + r][jb + kk];
        float4 wa = *(const float4*)&Wl[kk][tx * 8];
        float4 wb4 = *(const float4*)&Wl[kk][tx * 8 + 4];
        float wv[8] = {wa.x, wa.y, wa.z, wa.w, wb4.x, wb4.y, wb4.z, wb4.w};
        #pragma unroll
        for (int r = 0; r < 4; ++r)
          #pragma unroll
          for (int c = 0; c < 8; ++c)
            acc[r][c] += ss[r] * wv[c];
      }
      __syncthreads();
    }
  }

  // epilogue: tanh + store
  #pragma unroll
  for (int r = 0; r < 4; ++r) {
    long long vv = v0 + ty * 4 + r;
    if (vv >= N) continue;
    float* op = out + vv * D + tx * 8;
    float vals[8];
    #pragma unroll
    for (int c = 0; c < 8; ++c) vals[c] = tanhf(acc[r][c]);
    *(float4*)(op + 0) = make_float4(vals[0], vals[1], vals[2], vals[3]);
    *(float4*)(op + 4) = make_float4(vals[4], vals[5], vals[6], vals[7]);
  }
}

extern "C" void kernel_launch(void* const* d_in, const int* in_sizes, int n_in,
                              void* d_out, int out_size, void* d_ws, size_t ws_size,
                              hipStream_t stream) {
  const float* x    = (const float*)d_in[0];
  const float* W    = (const float*)d_in[1];
  const int*   u    = (const int*)d_in[2];
  const int*   v    = (const int*)d_in[3];
  const int*   widx = (const int*)d_in[4];

  long long N  = (long long)in_sizes[0] / D;
  int       NW = in_sizes[1] / (D * D);
  long long E  = (long long)in_sizes[2];
  float* out = (float*)d_out;

  int nTiles = (int)((N + BMT - 1) / BMT);
  int NB = NW * nTiles;

  // workspace layout
  char* ws = (char*)d_ws;
  size_t cntBytes = (size_t)NB * 16 * sizeof(int);
  int* cntPad    = (int*)ws;                      ws += cntBytes;
  int* cursorPad = (int*)ws;                      ws += cntBytes;
  int* starts    = (int*)ws;                      ws += ((size_t)NB + 1) * sizeof(int);
  // align to 16B
  ws = (char*)(((uintptr_t)ws + 15) & ~(uintptr_t)15);
  unsigned* sorted = (unsigned*)ws;               ws += (size_t)E * sizeof(unsigned);
  (void)ws_size;

  dim3 blk(256);
  int edgeGrid = (int)((E + 255) / 256);

  hipMemsetAsync(cntPad, 0, cntBytes, stream);
  hist_kernel<<<edgeGrid, blk, 0, stream>>>(v, widx, cntPad, E, nTiles);
  scan_kernel<<<1, 1024, 0, stream>>>(cntPad, starts, cursorPad, NB);
  scatter_ids_kernel<<<edgeGrid, blk, 0, stream>>>(u, v, widx, cursorPad, sorted,
                                                   E, nTiles);
  fused_kernel<<<nTiles, blk, 0, stream>>>(x, W, starts, sorted, out, N, nTiles, NW);
}

// Round 3
// 1847.871 us; speedup vs baseline: 2.1674x; 1.1214x over previous
//
#include <hip/hip_runtime.h>
#include <math.h>

#define D 128
#define BMT 64            // v-tile rows

typedef __attribute__((ext_vector_type(8))) short bf8;
typedef __attribute__((ext_vector_type(4))) float f32x4;

__device__ __forceinline__ unsigned short f2bf_rne(float f) {
  unsigned u = __float_as_uint(f);
  unsigned r = (u + 0x7FFFu + ((u >> 16) & 1u)) >> 16;
  return (unsigned short)r;
}
__device__ __forceinline__ float bf2f(unsigned short h) {
  return __uint_as_float(((unsigned)h) << 16);
}

// ---------- Phase A2: histogram of edges into (w, vtile) buckets ----------
__global__ __launch_bounds__(256) void hist_kernel(
    const int* __restrict__ v, const int* __restrict__ widx,
    int* __restrict__ cntPad, long long E, int nTiles) {
  long long e = (long long)blockIdx.x * blockDim.x + threadIdx.x;
  if (e >= E) return;
  int b = widx[e] * nTiles + (v[e] >> 6);
  atomicAdd(&cntPad[(long long)b * 16], 1);
}

// ---------- Phase A3: exclusive scan over NB buckets (single block) ----------
__global__ __launch_bounds__(1024) void scan_kernel(
    const int* __restrict__ cntPad, int* __restrict__ starts,
    int* __restrict__ cursorPad, int NB) {
  __shared__ int part[1024];
  int tid = threadIdx.x;
  int per = (NB + 1023) / 1024;      // <= 16 assumed
  int base = tid * per;
  int local[16];
  int sum = 0;
  for (int i = 0; i < per; ++i) {
    int idx = base + i;
    int c = (idx < NB) ? cntPad[(long long)idx * 16] : 0;
    local[i] = sum;
    sum += c;
  }
  part[tid] = sum;
  __syncthreads();
  for (int off = 1; off < 1024; off <<= 1) {
    int val = (tid >= off) ? part[tid - off] : 0;
    __syncthreads();
    part[tid] += val;
    __syncthreads();
  }
  int excl = (tid == 0) ? 0 : part[tid - 1];
  for (int i = 0; i < per; ++i) {
    int idx = base + i;
    if (idx < NB) {
      int s = excl + local[i];
      starts[idx] = s;
      cursorPad[(long long)idx * 16] = s;
    }
  }
  if (tid == 1023) starts[NB] = excl + sum;
}

// ---------- Phase A4: scatter packed edge records into bucket order ----------
// record: u (24 bits) | vlow (6 bits, v & 63) << 24
__global__ __launch_bounds__(256) void scatter_ids_kernel(
    const int* __restrict__ u, const int* __restrict__ v,
    const int* __restrict__ widx, int* __restrict__ cursorPad,
    unsigned* __restrict__ sorted, long long E, int nTiles) {
  long long e = (long long)blockIdx.x * blockDim.x + threadIdx.x;
  if (e >= E) return;
  int vv = v[e];
  int b = widx[e] * nTiles + (vv >> 6);
  int pos = atomicAdd(&cursorPad[(long long)b * 16], 1);
  sorted[pos] = (unsigned)u[e] | ((unsigned)(vv & 63) << 24);
}

// ---------- W -> bf16 hi + bf16 residual ----------
__global__ __launch_bounds__(256) void wconv_kernel(
    const float* __restrict__ W, unsigned short* __restrict__ Wbf,
    unsigned short* __restrict__ Wr, int total) {
  int i0 = (blockIdx.x * 256 + threadIdx.x) * 8;
  #pragma unroll
  for (int k = 0; k < 8; ++k) {
    int i = i0 + k;
    if (i < total) {
      float f = W[i];
      unsigned short hi = f2bf_rne(f);
      Wbf[i] = hi;
      Wr[i] = f2bf_rne(f - bf2f(hi));
    }
  }
}

// ---------- Phase B1: per-bucket aggregate into LDS, write bf16 S-tile ----
// One block per bucket b = w*nTiles + t. LDS is component-major so the
// per-lane ds_add hits bank=lane (conflict-free; 2 half-waves = free 2-way).
__global__ __launch_bounds__(256) void aggregate_kernel(
    const float* __restrict__ x, const int* __restrict__ starts,
    const unsigned* __restrict__ sorted, unsigned short* __restrict__ Sbf,
    long long NpadA, int nTiles) {
  __shared__ float Sc[4][BMT][32];   // 32 KB
  int tid = threadIdx.x;
  int b = blockIdx.x;

  // zero tile
  {
    float4* z = (float4*)&Sc[0][0][0];
    #pragma unroll
    for (int i = 0; i < 8; ++i) z[tid + i * 256] = make_float4(0.f, 0.f, 0.f, 0.f);
  }
  __syncthreads();

  int s0 = starts[b];
  int s1 = starts[b + 1];
  int hw = tid >> 5;        // half-wave id 0..7
  int lane = tid & 31;
  const float4* x4 = (const float4*)x;

  for (int i = s0 + hw * 4; i < s1; i += 32) {
    unsigned rec[4];
    float4 xv[4];
    #pragma unroll
    for (int k = 0; k < 4; ++k)
      if (i + k < s1) rec[k] = sorted[i + k];
    #pragma unroll
    for (int k = 0; k < 4; ++k)
      if (i + k < s1) xv[k] = x4[(size_t)(rec[k] & 0xFFFFFF) * 32 + lane];
    #pragma unroll
    for (int k = 0; k < 4; ++k) {
      if (i + k < s1) {
        int vl = (int)(rec[k] >> 24);
        atomicAdd(&Sc[0][vl][lane], xv[k].x);
        atomicAdd(&Sc[1][vl][lane], xv[k].y);
        atomicAdd(&Sc[2][vl][lane], xv[k].z);
        atomicAdd(&Sc[3][vl][lane], xv[k].w);
      }
    }
  }
  __syncthreads();

  // store 64x128 tile as bf16 (ushort2 per thread-iter, coalesced)
  int w = b / nTiles;
  int t = b - w * nTiles;
  ushort2* dst = (ushort2*)Sbf;
  size_t rowBase = (size_t)w * NpadA + (size_t)t * BMT;
  #pragma unroll
  for (int it = 0; it < 16; ++it) {
    int flat = it * 256 + tid;        // 0..4095
    int m = flat & 63;                // ushort2 index within row
    int r = flat >> 6;                // row 0..63
    float f0 = Sc[2 * (m & 1)][r][m >> 1];
    float f1 = Sc[2 * (m & 1) + 1][r][m >> 1];
    ushort2 o;
    o.x = f2bf_rne(f0);
    o.y = f2bf_rne(f1);
    dst[(rowBase + r) * 64 + m] = o;
  }
}

// ---------- Phase B2: grouped MFMA GEMM + tanh ----------
// out[v,i] = tanh( sum_w sum_j S[w,v,j] * W[w,i,j] )
// A = S (row=v, k=j), B[k][col] = W[col][j=k]. 128 rows per block, 4 waves,
// 32 rows per wave (2 m-tiles x 8 n-tiles), K = 8w x 128.
__global__ __launch_bounds__(256) void mfma_gemm_kernel(
    const unsigned short* __restrict__ Sbf, const unsigned short* __restrict__ Wbf,
    const unsigned short* __restrict__ Wr, float* __restrict__ out,
    long long N, long long NpadA, int NW) {
  int tid = threadIdx.x;
  int wv = tid >> 6;
  int l = tid & 63;
  int lrow = l & 15;
  int lk = (l >> 4) * 8;
  long long r0 = (long long)blockIdx.x * 128 + wv * 32;

  f32x4 acc[2][8];
  #pragma unroll
  for (int m = 0; m < 2; ++m)
    #pragma unroll
    for (int n = 0; n < 8; ++n) acc[m][n] = (f32x4)(0.f);

  for (int w = 0; w < NW; ++w) {
    const unsigned short* Sw = Sbf + (size_t)w * NpadA * D;
    const unsigned short* Wh = Wbf + (size_t)w * D * D;
    const unsigned short* Wl = Wr + (size_t)w * D * D;
    #pragma unroll
    for (int ks = 0; ks < 4; ++ks) {
      int k0 = ks * 32 + lk;
      bf8 a[2];
      #pragma unroll
      for (int m = 0; m < 2; ++m)
        a[m] = *(const bf8*)(Sw + (size_t)(r0 + m * 16 + lrow) * D + k0);
      #pragma unroll
      for (int n = 0; n < 8; ++n) {
        bf8 b0 = *(const bf8*)(Wh + (size_t)(n * 16 + lrow) * D + k0);
        bf8 b1 = *(const bf8*)(Wl + (size_t)(n * 16 + lrow) * D + k0);
        #pragma unroll
        for (int m = 0; m < 2; ++m) {
          acc[m][n] = __builtin_amdgcn_mfma_f32_16x16x32_bf16(a[m], b0, acc[m][n], 0, 0, 0);
          acc[m][n] = __builtin_amdgcn_mfma_f32_16x16x32_bf16(a[m], b1, acc[m][n], 0, 0, 0);
        }
      }
    }
  }

  // epilogue: C/D layout col=lane&15, row=(lane>>4)*4+reg
  int crow0 = (l >> 4) * 4;
  #pragma unroll
  for (int m = 0; m < 2; ++m) {
    long long vbase = r0 + m * 16 + crow0;
    #pragma unroll
    for (int rr = 0; rr < 4; ++rr) {
      long long v = vbase + rr;
      if (v < N) {
        float* op = out + v * D + lrow;
        #pragma unroll
        for (int n = 0; n < 8; ++n) op[n * 16] = tanhf(acc[m][n][rr]);
      }
    }
  }
}

extern "C" void kernel_launch(void* const* d_in, const int* in_sizes, int n_in,
                              void* d_out, int out_size, void* d_ws, size_t ws_size,
                              hipStream_t stream) {
  const float* x    = (const float*)d_in[0];
  const float* W    = (const float*)d_in[1];
  const int*   u    = (const int*)d_in[2];
  const int*   v    = (const int*)d_in[3];
  const int*   widx = (const int*)d_in[4];

  long long N  = (long long)in_sizes[0] / D;
  int       NW = in_sizes[1] / (D * D);
  long long E  = (long long)in_sizes[2];
  float* out = (float*)d_out;

  int nTiles = (int)((N + BMT - 1) / BMT);          // 1563
  int NB = NW * nTiles;                             // 12504
  long long rowsTiled = (long long)nTiles * BMT;    // 100032
  int gemmBlocks = (int)((rowsTiled + 127) / 128);  // 782
  long long NpadA = (long long)gemmBlocks * 128;    // 100096

  // workspace layout
  char* ws = (char*)d_ws;
  size_t cntBytes = (size_t)NB * 16 * sizeof(int);
  int* cntPad    = (int*)ws;                      ws += cntBytes;
  int* cursorPad = (int*)ws;                      ws += cntBytes;
  int* starts    = (int*)ws;                      ws += ((size_t)NB + 1) * sizeof(int);
  ws = (char*)(((uintptr_t)ws + 255) & ~(uintptr_t)255);
  unsigned short* Wbf = (unsigned short*)ws;      ws += (size_t)NW * D * D * 2;
  unsigned short* Wrs = (unsigned short*)ws;      ws += (size_t)NW * D * D * 2;
  unsigned* sorted = (unsigned*)ws;               ws += (size_t)E * sizeof(unsigned);
  ws = (char*)(((uintptr_t)ws + 255) & ~(uintptr_t)255);
  unsigned short* Sbf = (unsigned short*)ws;      ws += (size_t)NW * NpadA * D * 2;
  (void)ws_size;

  dim3 blk(256);
  int edgeGrid = (int)((E + 255) / 256);
  int wTotal = NW * D * D;
  int wGrid = (wTotal + 2047) / 2048;

  hipMemsetAsync(cntPad, 0, cntBytes, stream);
  hist_kernel<<<edgeGrid, blk, 0, stream>>>(v, widx, cntPad, E, nTiles);
  scan_kernel<<<1, 1024, 0, stream>>>(cntPad, starts, cursorPad, NB);
  scatter_ids_kernel<<<edgeGrid, blk, 0, stream>>>(u, v, widx, cursorPad, sorted,
                                                   E, nTiles);
  wconv_kernel<<<wGrid, blk, 0, stream>>>(W, Wbf, Wrs, wTotal);
  aggregate_kernel<<<NB, blk, 0, stream>>>(x, starts, sorted, Sbf, NpadA, nTiles);
  mfma_gemm_kernel<<<gemmBlocks, blk, 0, stream>>>(Sbf, Wbf, Wrs, out, N, NpadA, NW);
}

// Round 4
// 861.218 us; speedup vs baseline: 4.6504x; 2.1456x over previous
//
#include <hip/hip_runtime.h>
#include <math.h>

#define D 128
#define BMT 64            // v-tile rows per level-1 bucket

typedef __attribute__((ext_vector_type(8))) short bf8;
typedef __attribute__((ext_vector_type(4))) float f32x4;

__device__ __forceinline__ unsigned short f2bf_rne(float f) {
  unsigned u = __float_as_uint(f);
  unsigned r = (u + 0x7FFFu + ((u >> 16) & 1u)) >> 16;
  return (unsigned short)r;
}
__device__ __forceinline__ float bf2f(unsigned short h) {
  return __uint_as_float(((unsigned)h) << 16);
}

// ---------- fused histograms: level-1 (w,vtile) padded + level-2 (w,v) ----
__global__ __launch_bounds__(256) void hist_kernel(
    const int* __restrict__ v, const int* __restrict__ widx,
    int* __restrict__ cnt1Pad, int* __restrict__ cnt2,
    long long E, int nTiles, long long rowsTiled) {
  long long e = (long long)blockIdx.x * blockDim.x + threadIdx.x;
  if (e >= E) return;
  int vv = v[e];
  int ww = widx[e];
  int b1 = ww * nTiles + (vv >> 6);
  long long seg = (long long)ww * rowsTiled + vv;
  atomicAdd(&cnt1Pad[(long long)b1 * 16], 1);
  atomicAdd(&cnt2[seg], 1);
}

// ---------- level-1 exclusive scan over NB1 buckets (single block) ----------
__global__ __launch_bounds__(1024) void scan_kernel(
    const int* __restrict__ cnt1Pad, int* __restrict__ starts1, int NB1) {
  __shared__ int part[1024];
  int tid = threadIdx.x;
  int per = (NB1 + 1023) / 1024;      // <= 16 assumed
  int base = tid * per;
  int local[16];
  int sum = 0;
  for (int i = 0; i < per; ++i) {
    int idx = base + i;
    int c = (idx < NB1) ? cnt1Pad[(long long)idx * 16] : 0;
    local[i] = sum;
    sum += c;
  }
  part[tid] = sum;
  __syncthreads();
  for (int off = 1; off < 1024; off <<= 1) {
    int val = (tid >= off) ? part[tid - off] : 0;
    __syncthreads();
    part[tid] += val;
    __syncthreads();
  }
  int excl = (tid == 0) ? 0 : part[tid - 1];
  for (int i = 0; i < per; ++i) {
    int idx = base + i;
    if (idx < NB1) starts1[idx] = excl + local[i];
  }
  if (tid == 1023) starts1[NB1] = excl + sum;
}

// ---------- level-2 scan: one wave per level-1 bucket (64 segments) --------
__global__ __launch_bounds__(256) void scan2_kernel(
    const int* __restrict__ cnt2, const int* __restrict__ starts1,
    int* __restrict__ starts2, int* __restrict__ cursor2, int NB1) {
  int wv = threadIdx.x >> 6;
  int lane = threadIdx.x & 63;
  int b1 = blockIdx.x * 4 + wv;
  if (b1 >= NB1) return;
  long long seg = (long long)b1 * 64 + lane;
  int c = cnt2[seg];
  int val = c;
  #pragma unroll
  for (int off = 1; off < 64; off <<= 1) {
    int other = __shfl_up(val, off, 64);
    if (lane >= off) val += other;
  }
  int excl = val - c;
  int s = starts1[b1] + excl;
  starts2[seg] = s;
  cursor2[seg] = s;
  if (b1 == NB1 - 1 && lane == 63) starts2[seg + 1] = s + c;
}

// ---------- scatter edge source ids into segment order ----------
__global__ __launch_bounds__(256) void scatter_ids_kernel(
    const int* __restrict__ u, const int* __restrict__ v,
    const int* __restrict__ widx, int* __restrict__ cursor2,
    int* __restrict__ sortedU, long long E, long long rowsTiled) {
  long long e = (long long)blockIdx.x * blockDim.x + threadIdx.x;
  if (e >= E) return;
  long long seg = (long long)widx[e] * rowsTiled + v[e];
  int pos = atomicAdd(&cursor2[seg], 1);
  sortedU[pos] = u[e];
}

// ---------- W -> bf16 hi + bf16 residual ----------
__global__ __launch_bounds__(256) void wconv_kernel(
    const float* __restrict__ W, unsigned short* __restrict__ Wbf,
    unsigned short* __restrict__ Wr, int total) {
  int i0 = (blockIdx.x * 256 + threadIdx.x) * 8;
  #pragma unroll
  for (int k = 0; k < 8; ++k) {
    int i = i0 + k;
    if (i < total) {
      float f = W[i];
      unsigned short hi = f2bf_rne(f);
      Wbf[i] = hi;
      Wr[i] = f2bf_rne(f - bf2f(hi));
    }
  }
}

// ---------- gather: one wave per S-row; register sum; bf16 row write -------
// grid: (NpadA/4 blocks, NW). No LDS, no atomics, no barriers.
__global__ __launch_bounds__(256) void gather_kernel(
    const float* __restrict__ x, const int* __restrict__ starts2,
    const int* __restrict__ sortedU, unsigned short* __restrict__ Sbf,
    long long rowsTiled, long long NpadA) {
  int wv = threadIdx.x >> 6;
  int lane = threadIdx.x & 63;
  long long w = blockIdx.y;
  long long r = (long long)blockIdx.x * 4 + wv;
  if (r >= NpadA) return;

  float accx = 0.f, accy = 0.f;
  if (r < rowsTiled) {
    long long seg = w * rowsTiled + r;
    int s0 = starts2[seg];
    int s1 = starts2[seg + 1];
    const float2* x2 = (const float2*)x;
    int i = s0;
    for (; i + 4 <= s1; i += 4) {
      int u0 = sortedU[i], u1 = sortedU[i + 1];
      int u2 = sortedU[i + 2], u3 = sortedU[i + 3];
      float2 a0 = x2[(size_t)u0 * 64 + lane];
      float2 a1 = x2[(size_t)u1 * 64 + lane];
      float2 a2 = x2[(size_t)u2 * 64 + lane];
      float2 a3 = x2[(size_t)u3 * 64 + lane];
      accx += (a0.x + a1.x) + (a2.x + a3.x);
      accy += (a0.y + a1.y) + (a2.y + a3.y);
    }
    for (; i < s1; ++i) {
      int uu = sortedU[i];
      float2 a = x2[(size_t)uu * 64 + lane];
      accx += a.x;
      accy += a.y;
    }
  }
  ushort2 o;
  o.x = f2bf_rne(accx);
  o.y = f2bf_rne(accy);
  ((ushort2*)Sbf)[(w * NpadA + r) * 64 + lane] = o;
}

// ---------- grouped MFMA GEMM + tanh ----------
// out[v,i] = tanh( sum_w sum_j S[w,v,j] * W[w,i,j] )
__global__ __launch_bounds__(256) void mfma_gemm_kernel(
    const unsigned short* __restrict__ Sbf, const unsigned short* __restrict__ Wbf,
    const unsigned short* __restrict__ Wr, float* __restrict__ out,
    long long N, long long NpadA, int NW) {
  int tid = threadIdx.x;
  int wv = tid >> 6;
  int l = tid & 63;
  int lrow = l & 15;
  int lk = (l >> 4) * 8;
  long long r0 = (long long)blockIdx.x * 128 + wv * 32;

  f32x4 acc[2][8];
  #pragma unroll
  for (int m = 0; m < 2; ++m)
    #pragma unroll
    for (int n = 0; n < 8; ++n) acc[m][n] = (f32x4)(0.f);

  for (int w = 0; w < NW; ++w) {
    const unsigned short* Sw = Sbf + (size_t)w * NpadA * D;
    const unsigned short* Wh = Wbf + (size_t)w * D * D;
    const unsigned short* Wl = Wr + (size_t)w * D * D;
    #pragma unroll
    for (int ks = 0; ks < 4; ++ks) {
      int k0 = ks * 32 + lk;
      bf8 a[2];
      #pragma unroll
      for (int m = 0; m < 2; ++m)
        a[m] = *(const bf8*)(Sw + (size_t)(r0 + m * 16 + lrow) * D + k0);
      #pragma unroll
      for (int n = 0; n < 8; ++n) {
        bf8 b0 = *(const bf8*)(Wh + (size_t)(n * 16 + lrow) * D + k0);
        bf8 b1 = *(const bf8*)(Wl + (size_t)(n * 16 + lrow) * D + k0);
        #pragma unroll
        for (int m = 0; m < 2; ++m) {
          acc[m][n] = __builtin_amdgcn_mfma_f32_16x16x32_bf16(a[m], b0, acc[m][n], 0, 0, 0);
          acc[m][n] = __builtin_amdgcn_mfma_f32_16x16x32_bf16(a[m], b1, acc[m][n], 0, 0, 0);
        }
      }
    }
  }

  // epilogue: C/D layout col=lane&15, row=(lane>>4)*4+reg
  int crow0 = (l >> 4) * 4;
  #pragma unroll
  for (int m = 0; m < 2; ++m) {
    long long vbase = r0 + m * 16 + crow0;
    #pragma unroll
    for (int rr = 0; rr < 4; ++rr) {
      long long v = vbase + rr;
      if (v < N) {
        float* op = out + v * D + lrow;
        #pragma unroll
        for (int n = 0; n < 8; ++n) op[n * 16] = tanhf(acc[m][n][rr]);
      }
    }
  }
}

extern "C" void kernel_launch(void* const* d_in, const int* in_sizes, int n_in,
                              void* d_out, int out_size, void* d_ws, size_t ws_size,
                              hipStream_t stream) {
  const float* x    = (const float*)d_in[0];
  const float* W    = (const float*)d_in[1];
  const int*   u    = (const int*)d_in[2];
  const int*   v    = (const int*)d_in[3];
  const int*   widx = (const int*)d_in[4];

  long long N  = (long long)in_sizes[0] / D;
  int       NW = in_sizes[1] / (D * D);
  long long E  = (long long)in_sizes[2];
  float* out = (float*)d_out;

  int nTiles = (int)((N + BMT - 1) / BMT);          // 1563
  int NB1 = NW * nTiles;                            // 12504
  long long rowsTiled = (long long)nTiles * BMT;    // 100032
  long long NB2 = (long long)NW * rowsTiled;        // 800256
  int gemmBlocks = (int)((rowsTiled + 127) / 128);  // 782
  long long NpadA = (long long)gemmBlocks * 128;    // 100096

  // workspace layout
  char* ws = (char*)d_ws;
  int* cnt1Pad = (int*)ws;                        ws += (size_t)NB1 * 16 * sizeof(int);
  int* starts1 = (int*)ws;                        ws += ((size_t)NB1 + 1) * sizeof(int);
  ws = (char*)(((uintptr_t)ws + 255) & ~(uintptr_t)255);
  int* cnt2    = (int*)ws;                        ws += (size_t)NB2 * sizeof(int);
  int* starts2 = (int*)ws;                        ws += ((size_t)NB2 + 1) * sizeof(int);
  int* cursor2 = (int*)ws;                        ws += (size_t)NB2 * sizeof(int);
  int* sortedU = (int*)ws;                        ws += (size_t)E * sizeof(int);
  ws = (char*)(((uintptr_t)ws + 255) & ~(uintptr_t)255);
  unsigned short* Wbf = (unsigned short*)ws;      ws += (size_t)NW * D * D * 2;
  unsigned short* Wrs = (unsigned short*)ws;      ws += (size_t)NW * D * D * 2;
  ws = (char*)(((uintptr_t)ws + 255) & ~(uintptr_t)255);
  unsigned short* Sbf = (unsigned short*)ws;      ws += (size_t)NW * NpadA * D * 2;
  (void)ws_size;

  dim3 blk(256);
  int edgeGrid = (int)((E + 255) / 256);
  int wTotal = NW * D * D;
  int wGrid = (wTotal + 2047) / 2048;

  hipMemsetAsync(cnt1Pad, 0, (size_t)NB1 * 16 * sizeof(int), stream);
  hipMemsetAsync(cnt2, 0, (size_t)NB2 * sizeof(int), stream);
  hist_kernel<<<edgeGrid, blk, 0, stream>>>(v, widx, cnt1Pad, cnt2, E, nTiles,
                                            rowsTiled);
  scan_kernel<<<1, 1024, 0, stream>>>(cnt1Pad, starts1, NB1);
  scan2_kernel<<<(NB1 + 3) / 4, blk, 0, stream>>>(cnt2, starts1, starts2,
                                                  cursor2, NB1);
  scatter_ids_kernel<<<edgeGrid, blk, 0, stream>>>(u, v, widx, cursor2, sortedU,
                                                   E, rowsTiled);
  wconv_kernel<<<wGrid, blk, 0, stream>>>(W, Wbf, Wrs, wTotal);
  dim3 ggrid((unsigned)((NpadA + 3) / 4), (unsigned)NW);
  gather_kernel<<<ggrid, blk, 0, stream>>>(x, starts2, sortedU, Sbf,
                                           rowsTiled, NpadA);
  mfma_gemm_kernel<<<gemmBlocks, blk, 0, stream>>>(Sbf, Wbf, Wrs, out, N, NpadA, NW);
}

// Round 5
// 726.642 us; speedup vs baseline: 5.5117x; 1.1852x over previous
//
#include <hip/hip_runtime.h>
#include <math.h>

#define D 128

typedef __attribute__((ext_vector_type(8))) short bf8;
typedef __attribute__((ext_vector_type(4))) float f32x4;

__device__ __forceinline__ unsigned short f2bf_rne(float f) {
  unsigned u = __float_as_uint(f);
  unsigned r = (u + 0x7FFFu + ((u >> 16) & 1u)) >> 16;
  return (unsigned short)r;
}
__device__ __forceinline__ float bf2f(unsigned short h) {
  return __uint_as_float(((unsigned)h) << 16);
}

// ---------- histogram over (w,v) segments: 1 atomic/edge ----------
__global__ __launch_bounds__(256) void hist_kernel(
    const int* __restrict__ v, const int* __restrict__ widx,
    int* __restrict__ cnt2, long long E, long long N) {
  long long e = (long long)blockIdx.x * blockDim.x + threadIdx.x;
  if (e >= E) return;
  long long seg = (long long)widx[e] * N + v[e];
  atomicAdd(&cnt2[seg], 1);
}

// ---------- device scan, pass A: per-block (4096 elems) exclusive scan -----
__global__ __launch_bounds__(1024) void scanA_kernel(
    const int* __restrict__ cnt2, int* __restrict__ starts2,
    int* __restrict__ blkSums, long long NB2) {
  __shared__ int part[1024];
  int tid = threadIdx.x;
  long long base = (long long)blockIdx.x * 4096 + tid * 4;
  int c[4];
  #pragma unroll
  for (int i = 0; i < 4; ++i)
    c[i] = (base + i < NB2) ? cnt2[base + i] : 0;
  int loc[4];
  int sum = 0;
  #pragma unroll
  for (int i = 0; i < 4; ++i) { loc[i] = sum; sum += c[i]; }
  part[tid] = sum;
  __syncthreads();
  for (int off = 1; off < 1024; off <<= 1) {
    int val = (tid >= off) ? part[tid - off] : 0;
    __syncthreads();
    part[tid] += val;
    __syncthreads();
  }
  int excl = (tid == 0) ? 0 : part[tid - 1];
  #pragma unroll
  for (int i = 0; i < 4; ++i)
    if (base + i < NB2) starts2[base + i] = excl + loc[i];
  if (tid == 1023) blkSums[blockIdx.x] = part[1023];
}

// ---------- pass B: scan of block sums (<=256 blocks) ----------
__global__ __launch_bounds__(256) void scanB_kernel(
    int* __restrict__ blkSums, int* __restrict__ blkOff, int nBlk) {
  __shared__ int part[256];
  int tid = threadIdx.x;
  int s = (tid < nBlk) ? blkSums[tid] : 0;
  part[tid] = s;
  __syncthreads();
  for (int off = 1; off < 256; off <<= 1) {
    int val = (tid >= off) ? part[tid - off] : 0;
    __syncthreads();
    part[tid] += val;
    __syncthreads();
  }
  if (tid < nBlk) blkOff[tid] = part[tid] - s;   // exclusive
}

// ---------- pass C: add block offsets; produce starts2 + cursor2 ----------
__global__ __launch_bounds__(1024) void scanC_kernel(
    int* __restrict__ starts2, int* __restrict__ cursor2,
    const int* __restrict__ blkOff, long long NB2, int Etot) {
  int off = blkOff[blockIdx.x];
  long long base = (long long)blockIdx.x * 4096 + threadIdx.x * 4;
  #pragma unroll
  for (int i = 0; i < 4; ++i) {
    long long idx = base + i;
    if (idx < NB2) {
      int s = starts2[idx] + off;
      starts2[idx] = s;
      cursor2[idx] = s;
    }
  }
  if (blockIdx.x == 0 && threadIdx.x == 0) starts2[NB2] = Etot;
}

// ---------- scatter edge source ids into segment order ----------
__global__ __launch_bounds__(256) void scatter_ids_kernel(
    const int* __restrict__ u, const int* __restrict__ v,
    const int* __restrict__ widx, int* __restrict__ cursor2,
    int* __restrict__ sortedU, long long E, long long N) {
  long long e = (long long)blockIdx.x * blockDim.x + threadIdx.x;
  if (e >= E) return;
  long long seg = (long long)widx[e] * N + v[e];
  int pos = atomicAdd(&cursor2[seg], 1);
  sortedU[pos] = u[e];
}

// ---------- W -> bf16 hi + bf16 residual ----------
__global__ __launch_bounds__(256) void wconv_kernel(
    const float* __restrict__ W, unsigned short* __restrict__ Wbf,
    unsigned short* __restrict__ Wr, int total) {
  int i0 = (blockIdx.x * 256 + threadIdx.x) * 8;
  #pragma unroll
  for (int k = 0; k < 8; ++k) {
    int i = i0 + k;
    if (i < total) {
      float f = W[i];
      unsigned short hi = f2bf_rne(f);
      Wbf[i] = hi;
      Wr[i] = f2bf_rne(f - bf2f(hi));
    }
  }
}

// ---------- gather: one wave per S-row; register sum; bf16 row write -------
__global__ __launch_bounds__(256) void gather_kernel(
    const float* __restrict__ x, const int* __restrict__ starts2,
    const int* __restrict__ sortedU, unsigned short* __restrict__ Sbf,
    long long N, long long NpadA) {
  int wv = threadIdx.x >> 6;
  int lane = threadIdx.x & 63;
  long long w = blockIdx.y;
  long long r = (long long)blockIdx.x * 4 + wv;
  if (r >= NpadA) return;

  float accx = 0.f, accy = 0.f;
  if (r < N) {
    long long seg = w * N + r;
    int s0 = starts2[seg];
    int s1 = starts2[seg + 1];
    const float2* x2 = (const float2*)x;
    int i = s0;
    for (; i + 4 <= s1; i += 4) {
      int u0 = sortedU[i], u1 = sortedU[i + 1];
      int u2 = sortedU[i + 2], u3 = sortedU[i + 3];
      float2 a0 = x2[(size_t)u0 * 64 + lane];
      float2 a1 = x2[(size_t)u1 * 64 + lane];
      float2 a2 = x2[(size_t)u2 * 64 + lane];
      float2 a3 = x2[(size_t)u3 * 64 + lane];
      accx += (a0.x + a1.x) + (a2.x + a3.x);
      accy += (a0.y + a1.y) + (a2.y + a3.y);
    }
    for (; i < s1; ++i) {
      int uu = sortedU[i];
      float2 a = x2[(size_t)uu * 64 + lane];
      accx += a.x;
      accy += a.y;
    }
  }
  ushort2 o;
  o.x = f2bf_rne(accx);
  o.y = f2bf_rne(accy);
  ((ushort2*)Sbf)[(w * NpadA + r) * 64 + lane] = o;
}

// ---------- grouped MFMA GEMM + tanh ----------
// 2 waves/block, 32 rows/wave, 64 rows/block. B (Wh+Wr) loads shared via L1.
__global__ __launch_bounds__(128) void mfma_gemm_kernel(
    const unsigned short* __restrict__ Sbf, const unsigned short* __restrict__ Wbf,
    const unsigned short* __restrict__ Wr, float* __restrict__ out,
    long long N, long long NpadA, int NW) {
  int tid = threadIdx.x;
  int wv = tid >> 6;
  int l = tid & 63;
  int lrow = l & 15;
  int lk = (l >> 4) * 8;
  long long r0 = (long long)blockIdx.x * 64 + wv * 32;

  f32x4 acc[2][8];
  #pragma unroll
  for (int m = 0; m < 2; ++m)
    #pragma unroll
    for (int n = 0; n < 8; ++n) acc[m][n] = (f32x4)(0.f);

  for (int w = 0; w < NW; ++w) {
    const unsigned short* Sw = Sbf + (size_t)w * NpadA * D;
    const unsigned short* Wh = Wbf + (size_t)w * D * D;
    const unsigned short* Wl = Wr + (size_t)w * D * D;
    #pragma unroll
    for (int ks = 0; ks < 4; ++ks) {
      int k0 = ks * 32 + lk;
      bf8 a0 = *(const bf8*)(Sw + (size_t)(r0 + lrow) * D + k0);
      bf8 a1 = *(const bf8*)(Sw + (size_t)(r0 + 16 + lrow) * D + k0);
      #pragma unroll
      for (int np = 0; np < 4; ++np) {
        int n0 = np * 2, n1 = np * 2 + 1;
        bf8 bh0 = *(const bf8*)(Wh + (size_t)(n0 * 16 + lrow) * D + k0);
        bf8 br0 = *(const bf8*)(Wl + (size_t)(n0 * 16 + lrow) * D + k0);
        bf8 bh1 = *(const bf8*)(Wh + (size_t)(n1 * 16 + lrow) * D + k0);
        bf8 br1 = *(const bf8*)(Wl + (size_t)(n1 * 16 + lrow) * D + k0);
        acc[0][n0] = __builtin_amdgcn_mfma_f32_16x16x32_bf16(a0, bh0, acc[0][n0], 0, 0, 0);
        acc[1][n0] = __builtin_amdgcn_mfma_f32_16x16x32_bf16(a1, bh0, acc[1][n0], 0, 0, 0);
        acc[0][n1] = __builtin_amdgcn_mfma_f32_16x16x32_bf16(a0, bh1, acc[0][n1], 0, 0, 0);
        acc[1][n1] = __builtin_amdgcn_mfma_f32_16x16x32_bf16(a1, bh1, acc[1][n1], 0, 0, 0);
        acc[0][n0] = __builtin_amdgcn_mfma_f32_16x16x32_bf16(a0, br0, acc[0][n0], 0, 0, 0);
        acc[1][n0] = __builtin_amdgcn_mfma_f32_16x16x32_bf16(a1, br0, acc[1][n0], 0, 0, 0);
        acc[0][n1] = __builtin_amdgcn_mfma_f32_16x16x32_bf16(a0, br1, acc[0][n1], 0, 0, 0);
        acc[1][n1] = __builtin_amdgcn_mfma_f32_16x16x32_bf16(a1, br1, acc[1][n1], 0, 0, 0);
      }
    }
  }

  // epilogue: C/D layout col=lane&15, row=(lane>>4)*4+reg
  int crow0 = (l >> 4) * 4;
  #pragma unroll
  for (int m = 0; m < 2; ++m) {
    long long vbase = r0 + m * 16 + crow0;
    #pragma unroll
    for (int rr = 0; rr < 4; ++rr) {
      long long v = vbase + rr;
      if (v < N) {
        float* op = out + v * D + lrow;
        #pragma unroll
        for (int n = 0; n < 8; ++n) op[n * 16] = tanhf(acc[m][n][rr]);
      }
    }
  }
}

extern "C" void kernel_launch(void* const* d_in, const int* in_sizes, int n_in,
                              void* d_out, int out_size, void* d_ws, size_t ws_size,
                              hipStream_t stream) {
  const float* x    = (const float*)d_in[0];
  const float* W    = (const float*)d_in[1];
  const int*   u    = (const int*)d_in[2];
  const int*   v    = (const int*)d_in[3];
  const int*   widx = (const int*)d_in[4];

  long long N  = (long long)in_sizes[0] / D;
  int       NW = in_sizes[1] / (D * D);
  long long E  = (long long)in_sizes[2];
  float* out = (float*)d_out;

  long long NB2 = (long long)NW * N;                // 800000
  int gemmBlocks = (int)((N + 63) / 64);            // 1563
  long long NpadA = (long long)gemmBlocks * 64;     // 100032
  int nScanBlk = (int)((NB2 + 4095) / 4096);        // 196 (<=256 required)

  // workspace layout
  char* ws = (char*)d_ws;
  int* cnt2    = (int*)ws;                        ws += (size_t)NB2 * sizeof(int);
  int* starts2 = (int*)ws;                        ws += ((size_t)NB2 + 1) * sizeof(int);
  int* cursor2 = (int*)ws;                        ws += (size_t)NB2 * sizeof(int);
  int* blkSums = (int*)ws;                        ws += 256 * sizeof(int);
  int* blkOff  = (int*)ws;                        ws += 256 * sizeof(int);
  int* sortedU = (int*)ws;                        ws += (size_t)E * sizeof(int);
  ws = (char*)(((uintptr_t)ws + 255) & ~(uintptr_t)255);
  unsigned short* Wbf = (unsigned short*)ws;      ws += (size_t)NW * D * D * 2;
  unsigned short* Wrs = (unsigned short*)ws;      ws += (size_t)NW * D * D * 2;
  ws = (char*)(((uintptr_t)ws + 255) & ~(uintptr_t)255);
  unsigned short* Sbf = (unsigned short*)ws;      ws += (size_t)NW * NpadA * D * 2;
  (void)ws_size;

  dim3 blk(256);
  int edgeGrid = (int)((E + 255) / 256);
  int wTotal = NW * D * D;
  int wGrid = (wTotal + 2047) / 2048;

  hipMemsetAsync(cnt2, 0, (size_t)NB2 * sizeof(int), stream);
  hist_kernel<<<edgeGrid, blk, 0, stream>>>(v, widx, cnt2, E, N);
  scanA_kernel<<<nScanBlk, 1024, 0, stream>>>(cnt2, starts2, blkSums, NB2);
  scanB_kernel<<<1, 256, 0, stream>>>(blkSums, blkOff, nScanBlk);
  scanC_kernel<<<nScanBlk, 1024, 0, stream>>>(starts2, cursor2, blkOff, NB2,
                                              (int)E);
  scatter_ids_kernel<<<edgeGrid, blk, 0, stream>>>(u, v, widx, cursor2, sortedU,
                                                   E, N);
  wconv_kernel<<<wGrid, blk, 0, stream>>>(W, Wbf, Wrs, wTotal);
  dim3 ggrid((unsigned)((NpadA + 3) / 4), (unsigned)NW);
  gather_kernel<<<ggrid, blk, 0, stream>>>(x, starts2, sortedU, Sbf, N, NpadA);
  mfma_gemm_kernel<<<gemmBlocks, dim3(128), 0, stream>>>(Sbf, Wbf, Wrs, out,
                                                         N, NpadA, NW);
}

// Round 6
// 566.234 us; speedup vs baseline: 7.0731x; 1.2833x over previous
//
#include <hip/hip_runtime.h>
#include <math.h>

#define D 128

typedef __attribute__((ext_vector_type(8))) short bf8;
typedef __attribute__((ext_vector_type(4))) float f32x4;

__device__ __forceinline__ unsigned short f2bf_rne(float f) {
  unsigned u = __float_as_uint(f);
  unsigned r = (u + 0x7FFFu + ((u >> 16) & 1u)) >> 16;
  return (unsigned short)r;
}
__device__ __forceinline__ float bf2f(unsigned short h) {
  return __uint_as_float(((unsigned)h) << 16);
}

// ---------- histogram over (w,v) segments: 1 atomic/edge ----------
__global__ __launch_bounds__(256) void hist_kernel(
    const int* __restrict__ v, const int* __restrict__ widx,
    int* __restrict__ cnt2, long long E, long long N) {
  long long e = (long long)blockIdx.x * blockDim.x + threadIdx.x;
  if (e >= E) return;
  long long seg = (long long)widx[e] * N + v[e];
  atomicAdd(&cnt2[seg], 1);
}

// ---------- device scan, pass A ----------
__global__ __launch_bounds__(1024) void scanA_kernel(
    const int* __restrict__ cnt2, int* __restrict__ starts2,
    int* __restrict__ blkSums, long long NB2) {
  __shared__ int part[1024];
  int tid = threadIdx.x;
  long long base = (long long)blockIdx.x * 4096 + tid * 4;
  int c[4];
  #pragma unroll
  for (int i = 0; i < 4; ++i)
    c[i] = (base + i < NB2) ? cnt2[base + i] : 0;
  int loc[4];
  int sum = 0;
  #pragma unroll
  for (int i = 0; i < 4; ++i) { loc[i] = sum; sum += c[i]; }
  part[tid] = sum;
  __syncthreads();
  for (int off = 1; off < 1024; off <<= 1) {
    int val = (tid >= off) ? part[tid - off] : 0;
    __syncthreads();
    part[tid] += val;
    __syncthreads();
  }
  int excl = (tid == 0) ? 0 : part[tid - 1];
  #pragma unroll
  for (int i = 0; i < 4; ++i)
    if (base + i < NB2) starts2[base + i] = excl + loc[i];
  if (tid == 1023) blkSums[blockIdx.x] = part[1023];
}

// ---------- pass B ----------
__global__ __launch_bounds__(256) void scanB_kernel(
    int* __restrict__ blkSums, int* __restrict__ blkOff, int nBlk) {
  __shared__ int part[256];
  int tid = threadIdx.x;
  int s = (tid < nBlk) ? blkSums[tid] : 0;
  part[tid] = s;
  __syncthreads();
  for (int off = 1; off < 256; off <<= 1) {
    int val = (tid >= off) ? part[tid - off] : 0;
    __syncthreads();
    part[tid] += val;
    __syncthreads();
  }
  if (tid < nBlk) blkOff[tid] = part[tid] - s;   // exclusive
}

// ---------- pass C ----------
__global__ __launch_bounds__(1024) void scanC_kernel(
    int* __restrict__ starts2, int* __restrict__ cursor2,
    const int* __restrict__ blkOff, long long NB2, int Etot) {
  int off = blkOff[blockIdx.x];
  long long base = (long long)blockIdx.x * 4096 + threadIdx.x * 4;
  #pragma unroll
  for (int i = 0; i < 4; ++i) {
    long long idx = base + i;
    if (idx < NB2) {
      int s = starts2[idx] + off;
      starts2[idx] = s;
      cursor2[idx] = s;
    }
  }
  if (blockIdx.x == 0 && threadIdx.x == 0) starts2[NB2] = Etot;
}

// ---------- scatter edge source ids into segment order ----------
__global__ __launch_bounds__(256) void scatter_ids_kernel(
    const int* __restrict__ u, const int* __restrict__ v,
    const int* __restrict__ widx, int* __restrict__ cursor2,
    int* __restrict__ sortedU, long long E, long long N) {
  long long e = (long long)blockIdx.x * blockDim.x + threadIdx.x;
  if (e >= E) return;
  long long seg = (long long)widx[e] * N + v[e];
  int pos = atomicAdd(&cursor2[seg], 1);
  sortedU[pos] = u[e];
}

// ---------- W -> MFMA-fragment-packed bf16 hi+res ----------
// Wp layout: frag = (w*8 + n)*4 + ks; ushort offset = frag*1024 + p*512 + lane*8
// fragment content for lane l: W[w][n*16 + (l&15)][ks*32 + (l>>4)*8 .. +8)
__global__ __launch_bounds__(256) void wconv_pack_kernel(
    const float* __restrict__ W, unsigned short* __restrict__ Wp, int NW) {
  int idx = blockIdx.x * 256 + threadIdx.x;
  if (idx >= NW * 2048) return;
  int lane = idx & 63;
  int ks = (idx >> 6) & 3;
  int n  = (idx >> 8) & 7;
  int w  = idx >> 11;
  int row = n * 16 + (lane & 15);
  int col = ks * 32 + (lane >> 4) * 8;
  const float* src = W + (size_t)w * D * D + (size_t)row * D + col;
  unsigned short hi[8], re[8];
  #pragma unroll
  for (int e = 0; e < 8; ++e) {
    float f = src[e];
    unsigned short h = f2bf_rne(f);
    hi[e] = h;
    re[e] = f2bf_rne(f - bf2f(h));
  }
  int frag = (w * 8 + n) * 4 + ks;
  unsigned short* dst = Wp + (size_t)frag * 1024 + lane * 8;
  *(bf8*)dst = *(bf8*)hi;
  *(bf8*)(dst + 512) = *(bf8*)re;
}

// ---------- gather: 32-lane group per S-row, float4 lanes ----------
__global__ __launch_bounds__(256) void gather_kernel(
    const float* __restrict__ x, const int* __restrict__ starts2,
    const int* __restrict__ sortedU, unsigned short* __restrict__ Sbf,
    long long N, long long NpadA) {
  int grp = threadIdx.x >> 5;
  int lane = threadIdx.x & 31;
  long long w = blockIdx.y;
  long long r = (long long)blockIdx.x * 8 + grp;
  if (r >= NpadA) return;

  float ax = 0.f, ay = 0.f, az = 0.f, aw = 0.f;
  if (r < N) {
    long long seg = w * N + r;
    int s0 = starts2[seg];
    int s1 = starts2[seg + 1];
    const float4* x4 = (const float4*)x;
    int i = s0;
    for (; i + 4 <= s1; i += 4) {
      int u0 = sortedU[i], u1 = sortedU[i + 1];
      int u2 = sortedU[i + 2], u3 = sortedU[i + 3];
      float4 a0 = x4[(size_t)u0 * 32 + lane];
      float4 a1 = x4[(size_t)u1 * 32 + lane];
      float4 a2 = x4[(size_t)u2 * 32 + lane];
      float4 a3 = x4[(size_t)u3 * 32 + lane];
      ax += (a0.x + a1.x) + (a2.x + a3.x);
      ay += (a0.y + a1.y) + (a2.y + a3.y);
      az += (a0.z + a1.z) + (a2.z + a3.z);
      aw += (a0.w + a1.w) + (a2.w + a3.w);
    }
    for (; i < s1; ++i) {
      int uu = sortedU[i];
      float4 a = x4[(size_t)uu * 32 + lane];
      ax += a.x; ay += a.y; az += a.z; aw += a.w;
    }
  }
  ushort4 o;
  o.x = f2bf_rne(ax);
  o.y = f2bf_rne(ay);
  o.z = f2bf_rne(az);
  o.w = f2bf_rne(aw);
  *(ushort4*)(Sbf + (size_t)(w * NpadA + r) * D + lane * 4) = o;
}

// ---------- grouped MFMA GEMM + tanh (fragment-packed B) ----------
template<int NWT>
__global__ __launch_bounds__(128, 4) void mfma_gemm_kernel(
    const unsigned short* __restrict__ Sbf, const unsigned short* __restrict__ Wp,
    float* __restrict__ out, long long N, long long NpadA, int NWdyn) {
  const int NW = NWT ? NWT : NWdyn;
  int tid = threadIdx.x;
  int wv = tid >> 6;
  int l = tid & 63;
  int lrow = l & 15;
  int lkg = l >> 4;
  long long r0 = (long long)blockIdx.x * 64 + wv * 32;

  f32x4 acc[2][8];
  #pragma unroll
  for (int m = 0; m < 2; ++m)
    #pragma unroll
    for (int n = 0; n < 8; ++n) acc[m][n] = (f32x4)(0.f);

  #pragma unroll
  for (int w = 0; w < NW; ++w) {
    const unsigned short* Sw = Sbf + (size_t)w * NpadA * D;
    const unsigned short* Wf = Wp + (size_t)w * 32768;
    #pragma unroll
    for (int ks = 0; ks < 4; ++ks) {
      int k0 = ks * 32 + lkg * 8;
      bf8 a0 = *(const bf8*)(Sw + (size_t)(r0 + lrow) * D + k0);
      bf8 a1 = *(const bf8*)(Sw + (size_t)(r0 + 16 + lrow) * D + k0);
      #pragma unroll
      for (int n = 0; n < 8; ++n) {
        const unsigned short* bp = Wf + (size_t)(n * 4 + ks) * 1024 + l * 8;
        bf8 bh = *(const bf8*)bp;
        bf8 br = *(const bf8*)(bp + 512);
        acc[0][n] = __builtin_amdgcn_mfma_f32_16x16x32_bf16(a0, bh, acc[0][n], 0, 0, 0);
        acc[1][n] = __builtin_amdgcn_mfma_f32_16x16x32_bf16(a1, bh, acc[1][n], 0, 0, 0);
        acc[0][n] = __builtin_amdgcn_mfma_f32_16x16x32_bf16(a0, br, acc[0][n], 0, 0, 0);
        acc[1][n] = __builtin_amdgcn_mfma_f32_16x16x32_bf16(a1, br, acc[1][n], 0, 0, 0);
      }
    }
  }

  // epilogue: C/D layout col=lane&15, row=(lane>>4)*4+reg
  int crow0 = (l >> 4) * 4;
  #pragma unroll
  for (int m = 0; m < 2; ++m) {
    long long vbase = r0 + m * 16 + crow0;
    #pragma unroll
    for (int rr = 0; rr < 4; ++rr) {
      long long v = vbase + rr;
      if (v < N) {
        float* op = out + v * D + lrow;
        #pragma unroll
        for (int n = 0; n < 8; ++n) op[n * 16] = tanhf(acc[m][n][rr]);
      }
    }
  }
}

extern "C" void kernel_launch(void* const* d_in, const int* in_sizes, int n_in,
                              void* d_out, int out_size, void* d_ws, size_t ws_size,
                              hipStream_t stream) {
  const float* x    = (const float*)d_in[0];
  const float* W    = (const float*)d_in[1];
  const int*   u    = (const int*)d_in[2];
  const int*   v    = (const int*)d_in[3];
  const int*   widx = (const int*)d_in[4];

  long long N  = (long long)in_sizes[0] / D;
  int       NW = in_sizes[1] / (D * D);
  long long E  = (long long)in_sizes[2];
  float* out = (float*)d_out;

  long long NB2 = (long long)NW * N;                // 800000
  int gemmBlocks = (int)((N + 63) / 64);            // 1563
  long long NpadA = (long long)gemmBlocks * 64;     // 100032
  int nScanBlk = (int)((NB2 + 4095) / 4096);        // 196 (<=256 required)

  // workspace layout
  char* ws = (char*)d_ws;
  int* cnt2    = (int*)ws;                        ws += (size_t)NB2 * sizeof(int);
  int* starts2 = (int*)ws;                        ws += ((size_t)NB2 + 1) * sizeof(int);
  int* cursor2 = (int*)ws;                        ws += (size_t)NB2 * sizeof(int);
  int* blkSums = (int*)ws;                        ws += 256 * sizeof(int);
  int* blkOff  = (int*)ws;                        ws += 256 * sizeof(int);
  int* sortedU = (int*)ws;                        ws += (size_t)E * sizeof(int);
  ws = (char*)(((uintptr_t)ws + 255) & ~(uintptr_t)255);
  unsigned short* Wp = (unsigned short*)ws;       ws += (size_t)NW * 32768 * 2;
  ws = (char*)(((uintptr_t)ws + 255) & ~(uintptr_t)255);
  unsigned short* Sbf = (unsigned short*)ws;      ws += (size_t)NW * NpadA * D * 2;
  (void)ws_size;

  dim3 blk(256);
  int edgeGrid = (int)((E + 255) / 256);
  int wpGrid = (NW * 2048 + 255) / 256;

  hipMemsetAsync(cnt2, 0, (size_t)NB2 * sizeof(int), stream);
  hist_kernel<<<edgeGrid, blk, 0, stream>>>(v, widx, cnt2, E, N);
  scanA_kernel<<<nScanBlk, 1024, 0, stream>>>(cnt2, starts2, blkSums, NB2);
  scanB_kernel<<<1, 256, 0, stream>>>(blkSums, blkOff, nScanBlk);
  scanC_kernel<<<nScanBlk, 1024, 0, stream>>>(starts2, cursor2, blkOff, NB2,
                                              (int)E);
  scatter_ids_kernel<<<edgeGrid, blk, 0, stream>>>(u, v, widx, cursor2, sortedU,
                                                   E, N);
  wconv_pack_kernel<<<wpGrid, blk, 0, stream>>>(W, Wp, NW);
  dim3 ggrid((unsigned)((NpadA + 7) / 8), (unsigned)NW);
  gather_kernel<<<ggrid, blk, 0, stream>>>(x, starts2, sortedU, Sbf, N, NpadA);
  if (NW == 8) {
    mfma_gemm_kernel<8><<<gemmBlocks, dim3(128), 0, stream>>>(
        Sbf, Wp, out, N, NpadA, NW);
  } else {
    mfma_gemm_kernel<0><<<gemmBlocks, dim3(128), 0, stream>>>(
        Sbf, Wp, out, N, NpadA, NW);
  }
}

// Round 7
// 562.273 us; speedup vs baseline: 7.1229x; 1.0070x over previous
//
#include <hip/hip_runtime.h>
#include <math.h>

#define D 128

typedef __attribute__((ext_vector_type(8))) short bf8;
typedef __attribute__((ext_vector_type(4))) float f32x4;

__device__ __forceinline__ unsigned short f2bf_rne(float f) {
  unsigned u = __float_as_uint(f);
  unsigned r = (u + 0x7FFFu + ((u >> 16) & 1u)) >> 16;
  return (unsigned short)r;
}
__device__ __forceinline__ float bf2f(unsigned short h) {
  return __uint_as_float(((unsigned)h) << 16);
}

// ---------- histogram over (w,v) segments: 1 atomic/edge ----------
__global__ __launch_bounds__(256) void hist_kernel(
    const int* __restrict__ v, const int* __restrict__ widx,
    int* __restrict__ cnt2, long long E, long long N) {
  long long e = (long long)blockIdx.x * blockDim.x + threadIdx.x;
  if (e >= E) return;
  long long seg = (long long)widx[e] * N + v[e];
  atomicAdd(&cnt2[seg], 1);
}

// ---------- device scan, pass A ----------
__global__ __launch_bounds__(1024) void scanA_kernel(
    const int* __restrict__ cnt2, int* __restrict__ starts2,
    int* __restrict__ blkSums, long long NB2) {
  __shared__ int part[1024];
  int tid = threadIdx.x;
  long long base = (long long)blockIdx.x * 4096 + tid * 4;
  int c[4];
  #pragma unroll
  for (int i = 0; i < 4; ++i)
    c[i] = (base + i < NB2) ? cnt2[base + i] : 0;
  int loc[4];
  int sum = 0;
  #pragma unroll
  for (int i = 0; i < 4; ++i) { loc[i] = sum; sum += c[i]; }
  part[tid] = sum;
  __syncthreads();
  for (int off = 1; off < 1024; off <<= 1) {
    int val = (tid >= off) ? part[tid - off] : 0;
    __syncthreads();
    part[tid] += val;
    __syncthreads();
  }
  int excl = (tid == 0) ? 0 : part[tid - 1];
  #pragma unroll
  for (int i = 0; i < 4; ++i)
    if (base + i < NB2) starts2[base + i] = excl + loc[i];
  if (tid == 1023) blkSums[blockIdx.x] = part[1023];
}

// ---------- pass B ----------
__global__ __launch_bounds__(256) void scanB_kernel(
    int* __restrict__ blkSums, int* __restrict__ blkOff, int nBlk) {
  __shared__ int part[256];
  int tid = threadIdx.x;
  int s = (tid < nBlk) ? blkSums[tid] : 0;
  part[tid] = s;
  __syncthreads();
  for (int off = 1; off < 256; off <<= 1) {
    int val = (tid >= off) ? part[tid - off] : 0;
    __syncthreads();
    part[tid] += val;
    __syncthreads();
  }
  if (tid < nBlk) blkOff[tid] = part[tid] - s;   // exclusive
}

// ---------- pass C ----------
__global__ __launch_bounds__(1024) void scanC_kernel(
    int* __restrict__ starts2, int* __restrict__ cursor2,
    const int* __restrict__ blkOff, long long NB2, int Etot) {
  int off = blkOff[blockIdx.x];
  long long base = (long long)blockIdx.x * 4096 + threadIdx.x * 4;
  #pragma unroll
  for (int i = 0; i < 4; ++i) {
    long long idx = base + i;
    if (idx < NB2) {
      int s = starts2[idx] + off;
      starts2[idx] = s;
      cursor2[idx] = s;
    }
  }
  if (blockIdx.x == 0 && threadIdx.x == 0) starts2[NB2] = Etot;
}

// ---------- scatter edge source ids into segment order ----------
__global__ __launch_bounds__(256) void scatter_ids_kernel(
    const int* __restrict__ u, const int* __restrict__ v,
    const int* __restrict__ widx, int* __restrict__ cursor2,
    int* __restrict__ sortedU, long long E, long long N) {
  long long e = (long long)blockIdx.x * blockDim.x + threadIdx.x;
  if (e >= E) return;
  long long seg = (long long)widx[e] * N + v[e];
  int pos = atomicAdd(&cursor2[seg], 1);
  sortedU[pos] = u[e];
}

// ---------- W -> MFMA-fragment-packed bf16 hi+res ----------
// Wp layout: frag = (w*8 + n)*4 + ks; ushort offset = frag*1024 + p*512 + lane*8
__global__ __launch_bounds__(256) void wconv_pack_kernel(
    const float* __restrict__ W, unsigned short* __restrict__ Wp, int NW) {
  int idx = blockIdx.x * 256 + threadIdx.x;
  if (idx >= NW * 2048) return;
  int lane = idx & 63;
  int ks = (idx >> 6) & 3;
  int n  = (idx >> 8) & 7;
  int w  = idx >> 11;
  int row = n * 16 + (lane & 15);
  int col = ks * 32 + (lane >> 4) * 8;
  const float* src = W + (size_t)w * D * D + (size_t)row * D + col;
  unsigned short hi[8], re[8];
  #pragma unroll
  for (int e = 0; e < 8; ++e) {
    float f = src[e];
    unsigned short h = f2bf_rne(f);
    hi[e] = h;
    re[e] = f2bf_rne(f - bf2f(h));
  }
  int frag = (w * 8 + n) * 4 + ks;
  unsigned short* dst = Wp + (size_t)frag * 1024 + lane * 8;
  *(bf8*)dst = *(bf8*)hi;
  *(bf8*)(dst + 512) = *(bf8*)re;
}

// ---------- gather + pack: one block per (w, 16-row tile) ----------
// Accumulates 16 S-rows (32-lane groups, float4 lanes), stages in LDS, then
// re-emits in MFMA A-fragment order: frag=(w*nt16+rt)*4+ks holds lane l ->
// row rt*16+(l&15), cols ks*32+(l>>4)*8..+8, 16B/lane contiguous (1KB/frag).
__global__ __launch_bounds__(256) void gather_pack_kernel(
    const float* __restrict__ x, const int* __restrict__ starts2,
    const int* __restrict__ sortedU, unsigned short* __restrict__ Sp,
    long long N, long long nt16) {
  __shared__ float T[16][132];
  int tid = threadIdx.x;
  long long w = blockIdx.y;
  long long rt = blockIdx.x;
  long long r0 = rt * 16;
  int grp = tid >> 5;
  int lane = tid & 31;

  #pragma unroll
  for (int rr = 0; rr < 2; ++rr) {
    int rloc = grp + rr * 8;
    long long r = r0 + rloc;
    float ax = 0.f, ay = 0.f, az = 0.f, aw = 0.f;
    if (r < N) {
      long long seg = w * N + r;
      int s0 = starts2[seg];
      int s1 = starts2[seg + 1];
      const float4* x4 = (const float4*)x;
      int i = s0;
      for (; i + 4 <= s1; i += 4) {
        int u0 = sortedU[i], u1 = sortedU[i + 1];
        int u2 = sortedU[i + 2], u3 = sortedU[i + 3];
        float4 a0 = x4[(size_t)u0 * 32 + lane];
        float4 a1 = x4[(size_t)u1 * 32 + lane];
        float4 a2 = x4[(size_t)u2 * 32 + lane];
        float4 a3 = x4[(size_t)u3 * 32 + lane];
        ax += (a0.x + a1.x) + (a2.x + a3.x);
        ay += (a0.y + a1.y) + (a2.y + a3.y);
        az += (a0.z + a1.z) + (a2.z + a3.z);
        aw += (a0.w + a1.w) + (a2.w + a3.w);
      }
      for (; i < s1; ++i) {
        int uu = sortedU[i];
        float4 a = x4[(size_t)uu * 32 + lane];
        ax += a.x; ay += a.y; az += a.z; aw += a.w;
      }
    }
    *(float4*)&T[rloc][lane * 4] = make_float4(ax, ay, az, aw);
  }
  __syncthreads();

  // pack: thread t -> ks = t>>6, fragment lane l = t&63
  int ks = tid >> 6;
  int l = tid & 63;
  const float* src = &T[l & 15][ks * 32 + (l >> 4) * 8];
  unsigned short o[8];
  #pragma unroll
  for (int e = 0; e < 8; ++e) o[e] = f2bf_rne(src[e]);
  size_t frag = ((size_t)w * nt16 + rt) * 4 + ks;
  *(bf8*)(Sp + frag * 512 + (size_t)l * 8) = *(bf8*)o;
}

// ---------- grouped MFMA GEMM + tanh (fragment-packed A and B) ----------
template<int NWT>
__global__ __launch_bounds__(128, 2) void mfma_gemm_kernel(
    const unsigned short* __restrict__ Sp, const unsigned short* __restrict__ Wp,
    float* __restrict__ out, long long N, long long nt16, int NWdyn) {
  const int NW = NWT ? NWT : NWdyn;
  int tid = threadIdx.x;
  int wv = tid >> 6;
  int l = tid & 63;
  int lrow = l & 15;
  long long rt0 = (long long)blockIdx.x * 4 + wv * 2;   // two 16-row m-tiles
  long long r0 = rt0 * 16;

  f32x4 acc[2][8];
  #pragma unroll
  for (int m = 0; m < 2; ++m)
    #pragma unroll
    for (int n = 0; n < 8; ++n) acc[m][n] = (f32x4)(0.f);

  #pragma unroll
  for (int w = 0; w < NW; ++w) {
    const unsigned short* Sa = Sp + ((size_t)w * nt16 + rt0) * 2048 + (size_t)l * 8;
    const unsigned short* Wf = Wp + (size_t)w * 32768 + (size_t)l * 8;
    #pragma unroll
    for (int ks = 0; ks < 4; ++ks) {
      bf8 a0 = *(const bf8*)(Sa + ks * 512);
      bf8 a1 = *(const bf8*)(Sa + 2048 + ks * 512);
      #pragma unroll
      for (int n = 0; n < 8; ++n) {
        const unsigned short* bp = Wf + (size_t)(n * 4 + ks) * 1024;
        bf8 bh = *(const bf8*)bp;
        bf8 br = *(const bf8*)(bp + 512);
        acc[0][n] = __builtin_amdgcn_mfma_f32_16x16x32_bf16(a0, bh, acc[0][n], 0, 0, 0);
        acc[1][n] = __builtin_amdgcn_mfma_f32_16x16x32_bf16(a1, bh, acc[1][n], 0, 0, 0);
        acc[0][n] = __builtin_amdgcn_mfma_f32_16x16x32_bf16(a0, br, acc[0][n], 0, 0, 0);
        acc[1][n] = __builtin_amdgcn_mfma_f32_16x16x32_bf16(a1, br, acc[1][n], 0, 0, 0);
      }
    }
  }

  // epilogue: C/D layout col=lane&15, row=(lane>>4)*4+reg
  int crow0 = (l >> 4) * 4;
  #pragma unroll
  for (int m = 0; m < 2; ++m) {
    long long vbase = r0 + m * 16 + crow0;
    #pragma unroll
    for (int rr = 0; rr < 4; ++rr) {
      long long v = vbase + rr;
      if (v < N) {
        float* op = out + v * D + lrow;
        #pragma unroll
        for (int n = 0; n < 8; ++n) op[n * 16] = tanhf(acc[m][n][rr]);
      }
    }
  }
}

extern "C" void kernel_launch(void* const* d_in, const int* in_sizes, int n_in,
                              void* d_out, int out_size, void* d_ws, size_t ws_size,
                              hipStream_t stream) {
  const float* x    = (const float*)d_in[0];
  const float* W    = (const float*)d_in[1];
  const int*   u    = (const int*)d_in[2];
  const int*   v    = (const int*)d_in[3];
  const int*   widx = (const int*)d_in[4];

  long long N  = (long long)in_sizes[0] / D;
  int       NW = in_sizes[1] / (D * D);
  long long E  = (long long)in_sizes[2];
  float* out = (float*)d_out;

  long long NB2 = (long long)NW * N;                // 800000
  int gemmBlocks = (int)((N + 63) / 64);            // 1563
  long long NpadA = (long long)gemmBlocks * 64;     // 100032
  long long nt16 = NpadA / 16;                      // 6252
  int nScanBlk = (int)((NB2 + 4095) / 4096);        // 196 (<=256 required)

  // workspace layout
  char* ws = (char*)d_ws;
  int* cnt2    = (int*)ws;                        ws += (size_t)NB2 * sizeof(int);
  int* starts2 = (int*)ws;                        ws += ((size_t)NB2 + 1) * sizeof(int);
  int* cursor2 = (int*)ws;                        ws += (size_t)NB2 * sizeof(int);
  int* blkSums = (int*)ws;                        ws += 256 * sizeof(int);
  int* blkOff  = (int*)ws;                        ws += 256 * sizeof(int);
  int* sortedU = (int*)ws;                        ws += (size_t)E * sizeof(int);
  ws = (char*)(((uintptr_t)ws + 255) & ~(uintptr_t)255);
  unsigned short* Wp = (unsigned short*)ws;       ws += (size_t)NW * 32768 * 2;
  ws = (char*)(((uintptr_t)ws + 255) & ~(uintptr_t)255);
  unsigned short* Sp = (unsigned short*)ws;       ws += (size_t)NW * NpadA * D * 2;
  (void)ws_size;

  dim3 blk(256);
  int edgeGrid = (int)((E + 255) / 256);
  int wpGrid = (NW * 2048 + 255) / 256;

  hipMemsetAsync(cnt2, 0, (size_t)NB2 * sizeof(int), stream);
  hist_kernel<<<edgeGrid, blk, 0, stream>>>(v, widx, cnt2, E, N);
  scanA_kernel<<<nScanBlk, 1024, 0, stream>>>(cnt2, starts2, blkSums, NB2);
  scanB_kernel<<<1, 256, 0, stream>>>(blkSums, blkOff, nScanBlk);
  scanC_kernel<<<nScanBlk, 1024, 0, stream>>>(starts2, cursor2, blkOff, NB2,
                                              (int)E);
  scatter_ids_kernel<<<edgeGrid, blk, 0, stream>>>(u, v, widx, cursor2, sortedU,
                                                   E, N);
  wconv_pack_kernel<<<wpGrid, blk, 0, stream>>>(W, Wp, NW);
  dim3 ggrid((unsigned)nt16, (unsigned)NW);
  gather_pack_kernel<<<ggrid, blk, 0, stream>>>(x, starts2, sortedU, Sp, N, nt16);
  if (NW == 8) {
    mfma_gemm_kernel<8><<<gemmBlocks, dim3(128), 0, stream>>>(
        Sp, Wp, out, N, nt16, NW);
  } else {
    mfma_gemm_kernel<0><<<gemmBlocks, dim3(128), 0, stream>>>(
        Sp, Wp, out, N, nt16, NW);
  }
}

// Round 8
// 520.074 us; speedup vs baseline: 7.7009x; 1.0811x over previous
//
#include <hip/hip_runtime.h>
#include <math.h>

#define D 128

typedef __attribute__((ext_vector_type(8))) short bf8;
typedef __attribute__((ext_vector_type(4))) float f32x4;

__device__ __forceinline__ unsigned short f2bf_rne(float f) {
  unsigned u = __float_as_uint(f);
  unsigned r = (u + 0x7FFFu + ((u >> 16) & 1u)) >> 16;
  return (unsigned short)r;
}
__device__ __forceinline__ float bf2f(unsigned short h) {
  return __uint_as_float(((unsigned)h) << 16);
}

// ---------- histogram over (w,v) segments: 1 atomic/edge ----------
__global__ __launch_bounds__(256) void hist_kernel(
    const int* __restrict__ v, const int* __restrict__ widx,
    int* __restrict__ cnt2, long long E, long long N) {
  long long e = (long long)blockIdx.x * blockDim.x + threadIdx.x;
  if (e >= E) return;
  long long seg = (long long)widx[e] * N + v[e];
  atomicAdd(&cnt2[seg], 1);
}

// ---------- device scan, pass A ----------
__global__ __launch_bounds__(1024) void scanA_kernel(
    const int* __restrict__ cnt2, int* __restrict__ starts2,
    int* __restrict__ blkSums, long long NB2) {
  __shared__ int part[1024];
  int tid = threadIdx.x;
  long long base = (long long)blockIdx.x * 4096 + tid * 4;
  int c[4];
  #pragma unroll
  for (int i = 0; i < 4; ++i)
    c[i] = (base + i < NB2) ? cnt2[base + i] : 0;
  int loc[4];
  int sum = 0;
  #pragma unroll
  for (int i = 0; i < 4; ++i) { loc[i] = sum; sum += c[i]; }
  part[tid] = sum;
  __syncthreads();
  for (int off = 1; off < 1024; off <<= 1) {
    int val = (tid >= off) ? part[tid - off] : 0;
    __syncthreads();
    part[tid] += val;
    __syncthreads();
  }
  int excl = (tid == 0) ? 0 : part[tid - 1];
  #pragma unroll
  for (int i = 0; i < 4; ++i)
    if (base + i < NB2) starts2[base + i] = excl + loc[i];
  if (tid == 1023) blkSums[blockIdx.x] = part[1023];
}

// ---------- pass B ----------
__global__ __launch_bounds__(256) void scanB_kernel(
    int* __restrict__ blkSums, int* __restrict__ blkOff, int nBlk) {
  __shared__ int part[256];
  int tid = threadIdx.x;
  int s = (tid < nBlk) ? blkSums[tid] : 0;
  part[tid] = s;
  __syncthreads();
  for (int off = 1; off < 256; off <<= 1) {
    int val = (tid >= off) ? part[tid - off] : 0;
    __syncthreads();
    part[tid] += val;
    __syncthreads();
  }
  if (tid < nBlk) blkOff[tid] = part[tid] - s;   // exclusive
}

// ---------- pass C ----------
__global__ __launch_bounds__(1024) void scanC_kernel(
    int* __restrict__ starts2, int* __restrict__ cursor2,
    const int* __restrict__ blkOff, long long NB2, int Etot) {
  int off = blkOff[blockIdx.x];
  long long base = (long long)blockIdx.x * 4096 + threadIdx.x * 4;
  #pragma unroll
  for (int i = 0; i < 4; ++i) {
    long long idx = base + i;
    if (idx < NB2) {
      int s = starts2[idx] + off;
      starts2[idx] = s;
      cursor2[idx] = s;
    }
  }
  if (blockIdx.x == 0 && threadIdx.x == 0) starts2[NB2] = Etot;
}

// ---------- scatter edge source ids into segment order ----------
__global__ __launch_bounds__(256) void scatter_ids_kernel(
    const int* __restrict__ u, const int* __restrict__ v,
    const int* __restrict__ widx, int* __restrict__ cursor2,
    int* __restrict__ sortedU, long long E, long long N) {
  long long e = (long long)blockIdx.x * blockDim.x + threadIdx.x;
  if (e >= E) return;
  long long seg = (long long)widx[e] * N + v[e];
  int pos = atomicAdd(&cursor2[seg], 1);
  sortedU[pos] = u[e];
}

// ---------- W -> MFMA-fragment-packed bf16 hi+res ----------
// Wp layout: frag = (w*8 + n)*4 + ks; ushort offset = frag*1024 + p*512 + lane*8
__global__ __launch_bounds__(256) void wconv_pack_kernel(
    const float* __restrict__ W, unsigned short* __restrict__ Wp, int NW) {
  int idx = blockIdx.x * 256 + threadIdx.x;
  if (idx >= NW * 2048) return;
  int lane = idx & 63;
  int ks = (idx >> 6) & 3;
  int n  = (idx >> 8) & 7;
  int w  = idx >> 11;
  int row = n * 16 + (lane & 15);
  int col = ks * 32 + (lane >> 4) * 8;
  const float* src = W + (size_t)w * D * D + (size_t)row * D + col;
  unsigned short hi[8], re[8];
  #pragma unroll
  for (int e = 0; e < 8; ++e) {
    float f = src[e];
    unsigned short h = f2bf_rne(f);
    hi[e] = h;
    re[e] = f2bf_rne(f - bf2f(h));
  }
  int frag = (w * 8 + n) * 4 + ks;
  unsigned short* dst = Wp + (size_t)frag * 1024 + lane * 8;
  *(bf8*)dst = *(bf8*)hi;
  *(bf8*)(dst + 512) = *(bf8*)re;
}

// ---------- gather + pack: one block per (w, 16-row tile) ----------
// A-fragment order: frag=(w*nt16+rt)*4+ks holds lane l ->
// row rt*16+(l&15), cols ks*32+(l>>4)*8..+8, 16B/lane contiguous (1KB/frag).
__global__ __launch_bounds__(256) void gather_pack_kernel(
    const float* __restrict__ x, const int* __restrict__ starts2,
    const int* __restrict__ sortedU, unsigned short* __restrict__ Sp,
    long long N, long long nt16) {
  __shared__ float T[16][132];
  int tid = threadIdx.x;
  long long w = blockIdx.y;
  long long rt = blockIdx.x;
  long long r0 = rt * 16;
  int grp = tid >> 5;
  int lane = tid & 31;

  #pragma unroll
  for (int rr = 0; rr < 2; ++rr) {
    int rloc = grp + rr * 8;
    long long r = r0 + rloc;
    float ax = 0.f, ay = 0.f, az = 0.f, aw = 0.f;
    if (r < N) {
      long long seg = w * N + r;
      int s0 = starts2[seg];
      int s1 = starts2[seg + 1];
      const float4* x4 = (const float4*)x;
      int i = s0;
      for (; i + 4 <= s1; i += 4) {
        int u0 = sortedU[i], u1 = sortedU[i + 1];
        int u2 = sortedU[i + 2], u3 = sortedU[i + 3];
        float4 a0 = x4[(size_t)u0 * 32 + lane];
        float4 a1 = x4[(size_t)u1 * 32 + lane];
        float4 a2 = x4[(size_t)u2 * 32 + lane];
        float4 a3 = x4[(size_t)u3 * 32 + lane];
        ax += (a0.x + a1.x) + (a2.x + a3.x);
        ay += (a0.y + a1.y) + (a2.y + a3.y);
        az += (a0.z + a1.z) + (a2.z + a3.z);
        aw += (a0.w + a1.w) + (a2.w + a3.w);
      }
      for (; i < s1; ++i) {
        int uu = sortedU[i];
        float4 a = x4[(size_t)uu * 32 + lane];
        ax += a.x; ay += a.y; az += a.z; aw += a.w;
      }
    }
    *(float4*)&T[rloc][lane * 4] = make_float4(ax, ay, az, aw);
  }
  __syncthreads();

  int ks = tid >> 6;
  int l = tid & 63;
  const float* src = &T[l & 15][ks * 32 + (l >> 4) * 8];
  unsigned short o[8];
  #pragma unroll
  for (int e = 0; e < 8; ++e) o[e] = f2bf_rne(src[e]);
  size_t frag = ((size_t)w * nt16 + rt) * 4 + ks;
  *(bf8*)(Sp + frag * 512 + (size_t)l * 8) = *(bf8*)o;
}

// ---------- grouped MFMA GEMM + tanh ----------
// 256 threads = 4 waves; block tile 64 rows x 128 cols; wave tile 32x64.
// Explicit register double-buffer: step s+1's 10 fragments load while step
// s's 16 MFMAs issue.
template<int NWT>
__global__ __launch_bounds__(256, 2) void mfma_gemm_kernel(
    const unsigned short* __restrict__ Sp, const unsigned short* __restrict__ Wp,
    float* __restrict__ out, long long N, long long nt16, int NWdyn) {
  int tid = threadIdx.x;
  int wv = tid >> 6;
  int wr = wv >> 1;          // row half (0..1) -> 32 rows
  int wc = wv & 1;           // col half (0..1) -> 64 cols
  int l = tid & 63;
  long long rtBase = (long long)blockIdx.x * 4 + wr * 2;

  const unsigned short* SA = Sp + (size_t)rtBase * 2048 + (size_t)l * 8;
  const unsigned short* WB = Wp + (size_t)wc * 16384 + (size_t)l * 8;
  const size_t wStrideS = (size_t)nt16 * 2048;

  f32x4 acc[2][4];
  #pragma unroll
  for (int m = 0; m < 2; ++m)
    #pragma unroll
    for (int n = 0; n < 4; ++n) acc[m][n] = (f32x4)(0.f);

  if (NWT == 8) {
    bf8 a[2][2], bh[2][4], br[2][4];
    // prologue: load step 0 into buf 0
    {
      const unsigned short* sa = SA;
      a[0][0] = *(const bf8*)(sa);
      a[0][1] = *(const bf8*)(sa + 2048);
      const unsigned short* wb = WB;
      #pragma unroll
      for (int n = 0; n < 4; ++n) {
        bh[0][n] = *(const bf8*)(wb + n * 4096);
        br[0][n] = *(const bf8*)(wb + n * 4096 + 512);
      }
    }
    #pragma unroll
    for (int s = 0; s < 32; ++s) {
      const int buf = s & 1;
      const int nxt = buf ^ 1;
      if (s + 1 < 32) {
        const int w2 = (s + 1) >> 2, ks2 = (s + 1) & 3;
        const unsigned short* sa = SA + (size_t)w2 * wStrideS + ks2 * 512;
        a[nxt][0] = *(const bf8*)(sa);
        a[nxt][1] = *(const bf8*)(sa + 2048);
        const unsigned short* wb = WB + (size_t)w2 * 32768 + ks2 * 1024;
        #pragma unroll
        for (int n = 0; n < 4; ++n) {
          bh[nxt][n] = *(const bf8*)(wb + n * 4096);
          br[nxt][n] = *(const bf8*)(wb + n * 4096 + 512);
        }
      }
      #pragma unroll
      for (int n = 0; n < 4; ++n)
        #pragma unroll
        for (int m = 0; m < 2; ++m) {
          acc[m][n] = __builtin_amdgcn_mfma_f32_16x16x32_bf16(a[buf][m], bh[buf][n], acc[m][n], 0, 0, 0);
          acc[m][n] = __builtin_amdgcn_mfma_f32_16x16x32_bf16(a[buf][m], br[buf][n], acc[m][n], 0, 0, 0);
        }
    }
  } else {
    // dynamic-NW fallback: single-buffered, static indices only
    for (int w = 0; w < NWdyn; ++w) {
      #pragma unroll
      for (int ks = 0; ks < 4; ++ks) {
        const unsigned short* sa = SA + (size_t)w * wStrideS + ks * 512;
        bf8 a0 = *(const bf8*)(sa);
        bf8 a1 = *(const bf8*)(sa + 2048);
        const unsigned short* wb = WB + (size_t)w * 32768 + ks * 1024;
        #pragma unroll
        for (int n = 0; n < 4; ++n) {
          bf8 bh0 = *(const bf8*)(wb + n * 4096);
          bf8 br0 = *(const bf8*)(wb + n * 4096 + 512);
          acc[0][n] = __builtin_amdgcn_mfma_f32_16x16x32_bf16(a0, bh0, acc[0][n], 0, 0, 0);
          acc[1][n] = __builtin_amdgcn_mfma_f32_16x16x32_bf16(a1, bh0, acc[1][n], 0, 0, 0);
          acc[0][n] = __builtin_amdgcn_mfma_f32_16x16x32_bf16(a0, br0, acc[0][n], 0, 0, 0);
          acc[1][n] = __builtin_amdgcn_mfma_f32_16x16x32_bf16(a1, br0, acc[1][n], 0, 0, 0);
        }
      }
    }
  }

  // epilogue: C/D layout col=lane&15, row=(lane>>4)*4+reg
  int lrow = l & 15;
  int crow0 = (l >> 4) * 4;
  #pragma unroll
  for (int m = 0; m < 2; ++m) {
    long long vbase = (rtBase + m) * 16 + crow0;
    #pragma unroll
    for (int rr = 0; rr < 4; ++rr) {
      long long v = vbase + rr;
      if (v < N) {
        float* op = out + v * D + wc * 64 + lrow;
        #pragma unroll
        for (int n = 0; n < 4; ++n) op[n * 16] = tanhf(acc[m][n][rr]);
      }
    }
  }
}

extern "C" void kernel_launch(void* const* d_in, const int* in_sizes, int n_in,
                              void* d_out, int out_size, void* d_ws, size_t ws_size,
                              hipStream_t stream) {
  const float* x    = (const float*)d_in[0];
  const float* W    = (const float*)d_in[1];
  const int*   u    = (const int*)d_in[2];
  const int*   v    = (const int*)d_in[3];
  const int*   widx = (const int*)d_in[4];

  long long N  = (long long)in_sizes[0] / D;
  int       NW = in_sizes[1] / (D * D);
  long long E  = (long long)in_sizes[2];
  float* out = (float*)d_out;

  long long NB2 = (long long)NW * N;                // 800000
  int gemmBlocks = (int)((N + 63) / 64);            // 1563
  long long NpadA = (long long)gemmBlocks * 64;     // 100032
  long long nt16 = NpadA / 16;                      // 6252
  int nScanBlk = (int)((NB2 + 4095) / 4096);        // 196 (<=256 required)

  // workspace layout
  char* ws = (char*)d_ws;
  int* cnt2    = (int*)ws;                        ws += (size_t)NB2 * sizeof(int);
  int* starts2 = (int*)ws;                        ws += ((size_t)NB2 + 1) * sizeof(int);
  int* cursor2 = (int*)ws;                        ws += (size_t)NB2 * sizeof(int);
  int* blkSums = (int*)ws;                        ws += 256 * sizeof(int);
  int* blkOff  = (int*)ws;                        ws += 256 * sizeof(int);
  int* sortedU = (int*)ws;                        ws += (size_t)E * sizeof(int);
  ws = (char*)(((uintptr_t)ws + 255) & ~(uintptr_t)255);
  unsigned short* Wp = (unsigned short*)ws;       ws += (size_t)NW * 32768 * 2;
  ws = (char*)(((uintptr_t)ws + 255) & ~(uintptr_t)255);
  unsigned short* Sp = (unsigned short*)ws;       ws += (size_t)NW * NpadA * D * 2;
  (void)ws_size;

  dim3 blk(256);
  int edgeGrid = (int)((E + 255) / 256);
  int wpGrid = (NW * 2048 + 255) / 256;

  hipMemsetAsync(cnt2, 0, (size_t)NB2 * sizeof(int), stream);
  hist_kernel<<<edgeGrid, blk, 0, stream>>>(v, widx, cnt2, E, N);
  scanA_kernel<<<nScanBlk, 1024, 0, stream>>>(cnt2, starts2, blkSums, NB2);
  scanB_kernel<<<1, 256, 0, stream>>>(blkSums, blkOff, nScanBlk);
  scanC_kernel<<<nScanBlk, 1024, 0, stream>>>(starts2, cursor2, blkOff, NB2,
                                              (int)E);
  scatter_ids_kernel<<<edgeGrid, blk, 0, stream>>>(u, v, widx, cursor2, sortedU,
                                                   E, N);
  wconv_pack_kernel<<<wpGrid, blk, 0, stream>>>(W, Wp, NW);
  dim3 ggrid((unsigned)nt16, (unsigned)NW);
  gather_pack_kernel<<<ggrid, blk, 0, stream>>>(x, starts2, sortedU, Sp, N, nt16);
  if (NW == 8) {
    mfma_gemm_kernel<8><<<gemmBlocks, blk, 0, stream>>>(
        Sp, Wp, out, N, nt16, NW);
  } else {
    mfma_gemm_kernel<0><<<gemmBlocks, blk, 0, stream>>>(
        Sp, Wp, out, N, nt16, NW);
  }
}

// Round 9
// 500.010 us; speedup vs baseline: 8.0099x; 1.0401x over previous
//
#include <hip/hip_runtime.h>
#include <math.h>

#define D 128

typedef __attribute__((ext_vector_type(8))) short bf8;
typedef __attribute__((ext_vector_type(4))) float f32x4;

__device__ __forceinline__ unsigned short f2bf_rne(float f) {
  unsigned u = __float_as_uint(f);
  unsigned r = (u + 0x7FFFu + ((u >> 16) & 1u)) >> 16;
  return (unsigned short)r;
}
__device__ __forceinline__ float bf2f(unsigned short h) {
  return __uint_as_float(((unsigned)h) << 16);
}
__device__ __forceinline__ float bflo(unsigned p) {
  return __uint_as_float(p << 16);
}
__device__ __forceinline__ float bfhi(unsigned p) {
  return __uint_as_float(p & 0xFFFF0000u);
}

// ---------- histogram over (w,v) segments: 1 atomic/edge ----------
__global__ __launch_bounds__(256) void hist_kernel(
    const int* __restrict__ v, const int* __restrict__ widx,
    int* __restrict__ cnt2, long long E, long long N) {
  long long e = (long long)blockIdx.x * blockDim.x + threadIdx.x;
  if (e >= E) return;
  long long seg = (long long)widx[e] * N + v[e];
  atomicAdd(&cnt2[seg], 1);
}

// ---------- device scan, pass A ----------
__global__ __launch_bounds__(1024) void scanA_kernel(
    const int* __restrict__ cnt2, int* __restrict__ starts2,
    int* __restrict__ blkSums, long long NB2) {
  __shared__ int part[1024];
  int tid = threadIdx.x;
  long long base = (long long)blockIdx.x * 4096 + tid * 4;
  int c[4];
  #pragma unroll
  for (int i = 0; i < 4; ++i)
    c[i] = (base + i < NB2) ? cnt2[base + i] : 0;
  int loc[4];
  int sum = 0;
  #pragma unroll
  for (int i = 0; i < 4; ++i) { loc[i] = sum; sum += c[i]; }
  part[tid] = sum;
  __syncthreads();
  for (int off = 1; off < 1024; off <<= 1) {
    int val = (tid >= off) ? part[tid - off] : 0;
    __syncthreads();
    part[tid] += val;
    __syncthreads();
  }
  int excl = (tid == 0) ? 0 : part[tid - 1];
  #pragma unroll
  for (int i = 0; i < 4; ++i)
    if (base + i < NB2) starts2[base + i] = excl + loc[i];
  if (tid == 1023) blkSums[blockIdx.x] = part[1023];
}

// ---------- pass B ----------
__global__ __launch_bounds__(256) void scanB_kernel(
    int* __restrict__ blkSums, int* __restrict__ blkOff, int nBlk) {
  __shared__ int part[256];
  int tid = threadIdx.x;
  int s = (tid < nBlk) ? blkSums[tid] : 0;
  part[tid] = s;
  __syncthreads();
  for (int off = 1; off < 256; off <<= 1) {
    int val = (tid >= off) ? part[tid - off] : 0;
    __syncthreads();
    part[tid] += val;
    __syncthreads();
  }
  if (tid < nBlk) blkOff[tid] = part[tid] - s;   // exclusive
}

// ---------- pass C ----------
__global__ __launch_bounds__(1024) void scanC_kernel(
    int* __restrict__ starts2, int* __restrict__ cursor2,
    const int* __restrict__ blkOff, long long NB2, int Etot) {
  int off = blkOff[blockIdx.x];
  long long base = (long long)blockIdx.x * 4096 + threadIdx.x * 4;
  #pragma unroll
  for (int i = 0; i < 4; ++i) {
    long long idx = base + i;
    if (idx < NB2) {
      int s = starts2[idx] + off;
      starts2[idx] = s;
      cursor2[idx] = s;
    }
  }
  if (blockIdx.x == 0 && threadIdx.x == 0) starts2[NB2] = Etot;
}

// ---------- scatter edge source ids into segment order ----------
__global__ __launch_bounds__(256) void scatter_ids_kernel(
    const int* __restrict__ u, const int* __restrict__ v,
    const int* __restrict__ widx, int* __restrict__ cursor2,
    int* __restrict__ sortedU, long long E, long long N) {
  long long e = (long long)blockIdx.x * blockDim.x + threadIdx.x;
  if (e >= E) return;
  long long seg = (long long)widx[e] * N + v[e];
  int pos = atomicAdd(&cursor2[seg], 1);
  sortedU[pos] = u[e];
}

// ---------- x -> bf16 table ----------
__global__ __launch_bounds__(256) void xconv_kernel(
    const float* __restrict__ x, unsigned short* __restrict__ xbf,
    long long total) {
  long long i0 = ((long long)blockIdx.x * 256 + threadIdx.x) * 8;
  if (i0 + 8 > total) return;
  float4 f0 = *(const float4*)(x + i0);
  float4 f1 = *(const float4*)(x + i0 + 4);
  unsigned short o[8];
  o[0] = f2bf_rne(f0.x); o[1] = f2bf_rne(f0.y);
  o[2] = f2bf_rne(f0.z); o[3] = f2bf_rne(f0.w);
  o[4] = f2bf_rne(f1.x); o[5] = f2bf_rne(f1.y);
  o[6] = f2bf_rne(f1.z); o[7] = f2bf_rne(f1.w);
  *(bf8*)(xbf + i0) = *(bf8*)o;
}

// ---------- W -> MFMA-fragment-packed bf16 hi+res ----------
// Wp layout: frag = (w*8 + n)*4 + ks; ushort offset = frag*1024 + p*512 + lane*8
__global__ __launch_bounds__(256) void wconv_pack_kernel(
    const float* __restrict__ W, unsigned short* __restrict__ Wp, int NW) {
  int idx = blockIdx.x * 256 + threadIdx.x;
  if (idx >= NW * 2048) return;
  int lane = idx & 63;
  int ks = (idx >> 6) & 3;
  int n  = (idx >> 8) & 7;
  int w  = idx >> 11;
  int row = n * 16 + (lane & 15);
  int col = ks * 32 + (lane >> 4) * 8;
  const float* src = W + (size_t)w * D * D + (size_t)row * D + col;
  unsigned short hi[8], re[8];
  #pragma unroll
  for (int e = 0; e < 8; ++e) {
    float f = src[e];
    unsigned short h = f2bf_rne(f);
    hi[e] = h;
    re[e] = f2bf_rne(f - bf2f(h));
  }
  int frag = (w * 8 + n) * 4 + ks;
  unsigned short* dst = Wp + (size_t)frag * 1024 + lane * 8;
  *(bf8*)dst = *(bf8*)hi;
  *(bf8*)(dst + 512) = *(bf8*)re;
}

// ---------- gather + pack: one block per (w, 16-row tile), bf16 x ----------
// A-fragment order: frag=(w*nt16+rt)*4+ks holds lane l ->
// row rt*16+(l&15), cols ks*32+(l>>4)*8..+8, 16B/lane contiguous (1KB/frag).
__global__ __launch_bounds__(256) void gather_pack_kernel(
    const unsigned short* __restrict__ xbf, const int* __restrict__ starts2,
    const int* __restrict__ sortedU, unsigned short* __restrict__ Sp,
    long long N, long long nt16) {
  __shared__ float T[16][132];
  int tid = threadIdx.x;
  long long w = blockIdx.y;
  long long rt = blockIdx.x;
  long long r0 = rt * 16;
  int grp = tid >> 5;
  int lane = tid & 31;

  #pragma unroll
  for (int rr = 0; rr < 2; ++rr) {
    int rloc = grp + rr * 8;
    long long r = r0 + rloc;
    float ax = 0.f, ay = 0.f, az = 0.f, aw = 0.f;
    if (r < N) {
      long long seg = w * N + r;
      int s0 = starts2[seg];
      int s1 = starts2[seg + 1];
      const uint2* xb = (const uint2*)xbf;   // 4 bf16 per uint2
      int i = s0;
      for (; i + 4 <= s1; i += 4) {
        int u0 = sortedU[i], u1 = sortedU[i + 1];
        int u2 = sortedU[i + 2], u3 = sortedU[i + 3];
        uint2 a0 = xb[(size_t)u0 * 32 + lane];
        uint2 a1 = xb[(size_t)u1 * 32 + lane];
        uint2 a2 = xb[(size_t)u2 * 32 + lane];
        uint2 a3 = xb[(size_t)u3 * 32 + lane];
        ax += (bflo(a0.x) + bflo(a1.x)) + (bflo(a2.x) + bflo(a3.x));
        ay += (bfhi(a0.x) + bfhi(a1.x)) + (bfhi(a2.x) + bfhi(a3.x));
        az += (bflo(a0.y) + bflo(a1.y)) + (bflo(a2.y) + bflo(a3.y));
        aw += (bfhi(a0.y) + bfhi(a1.y)) + (bfhi(a2.y) + bfhi(a3.y));
      }
      for (; i < s1; ++i) {
        int uu = sortedU[i];
        uint2 a = xb[(size_t)uu * 32 + lane];
        ax += bflo(a.x); ay += bfhi(a.x);
        az += bflo(a.y); aw += bfhi(a.y);
      }
    }
    *(float4*)&T[rloc][lane * 4] = make_float4(ax, ay, az, aw);
  }
  __syncthreads();

  int ks = tid >> 6;
  int l = tid & 63;
  const float* src = &T[l & 15][ks * 32 + (l >> 4) * 8];
  unsigned short o[8];
  #pragma unroll
  for (int e = 0; e < 8; ++e) o[e] = f2bf_rne(src[e]);
  size_t frag = ((size_t)w * nt16 + rt) * 4 + ks;
  *(bf8*)(Sp + frag * 512 + (size_t)l * 8) = *(bf8*)o;
}

// ---------- grouped MFMA GEMM + tanh ----------
// 256 threads = 4 waves; block tile 64 rows x 128 cols; wave tile 32x64.
// Register double-buffer: step s+1's 10 fragments load during step s's MFMAs.
template<int NWT>
__global__ __launch_bounds__(256, 3) void mfma_gemm_kernel(
    const unsigned short* __restrict__ Sp, const unsigned short* __restrict__ Wp,
    float* __restrict__ out, long long N, long long nt16, int NWdyn) {
  int tid = threadIdx.x;
  int wv = tid >> 6;
  int wr = wv >> 1;          // row half (0..1) -> 32 rows
  int wc = wv & 1;           // col half (0..1) -> 64 cols
  int l = tid & 63;
  long long rtBase = (long long)blockIdx.x * 4 + wr * 2;

  const unsigned short* SA = Sp + (size_t)rtBase * 2048 + (size_t)l * 8;
  const unsigned short* WB = Wp + (size_t)wc * 16384 + (size_t)l * 8;
  const size_t wStrideS = (size_t)nt16 * 2048;

  f32x4 acc[2][4];
  #pragma unroll
  for (int m = 0; m < 2; ++m)
    #pragma unroll
    for (int n = 0; n < 4; ++n) acc[m][n] = (f32x4)(0.f);

  if (NWT == 8) {
    bf8 a[2][2], bh[2][4], br[2][4];
    {
      const unsigned short* sa = SA;
      a[0][0] = *(const bf8*)(sa);
      a[0][1] = *(const bf8*)(sa + 2048);
      const unsigned short* wb = WB;
      #pragma unroll
      for (int n = 0; n < 4; ++n) {
        bh[0][n] = *(const bf8*)(wb + n * 4096);
        br[0][n] = *(const bf8*)(wb + n * 4096 + 512);
      }
    }
    #pragma unroll
    for (int s = 0; s < 32; ++s) {
      const int buf = s & 1;
      const int nxt = buf ^ 1;
      if (s + 1 < 32) {
        const int w2 = (s + 1) >> 2, ks2 = (s + 1) & 3;
        const unsigned short* sa = SA + (size_t)w2 * wStrideS + ks2 * 512;
        a[nxt][0] = *(const bf8*)(sa);
        a[nxt][1] = *(const bf8*)(sa + 2048);
        const unsigned short* wb = WB + (size_t)w2 * 32768 + ks2 * 1024;
        #pragma unroll
        for (int n = 0; n < 4; ++n) {
          bh[nxt][n] = *(const bf8*)(wb + n * 4096);
          br[nxt][n] = *(const bf8*)(wb + n * 4096 + 512);
        }
      }
      #pragma unroll
      for (int n = 0; n < 4; ++n)
        #pragma unroll
        for (int m = 0; m < 2; ++m) {
          acc[m][n] = __builtin_amdgcn_mfma_f32_16x16x32_bf16(a[buf][m], bh[buf][n], acc[m][n], 0, 0, 0);
          acc[m][n] = __builtin_amdgcn_mfma_f32_16x16x32_bf16(a[buf][m], br[buf][n], acc[m][n], 0, 0, 0);
        }
    }
  } else {
    for (int w = 0; w < NWdyn; ++w) {
      #pragma unroll
      for (int ks = 0; ks < 4; ++ks) {
        const unsigned short* sa = SA + (size_t)w * wStrideS + ks * 512;
        bf8 a0 = *(const bf8*)(sa);
        bf8 a1 = *(const bf8*)(sa + 2048);
        const unsigned short* wb = WB + (size_t)w * 32768 + ks * 1024;
        #pragma unroll
        for (int n = 0; n < 4; ++n) {
          bf8 bh0 = *(const bf8*)(wb + n * 4096);
          bf8 br0 = *(const bf8*)(wb + n * 4096 + 512);
          acc[0][n] = __builtin_amdgcn_mfma_f32_16x16x32_bf16(a0, bh0, acc[0][n], 0, 0, 0);
          acc[1][n] = __builtin_amdgcn_mfma_f32_16x16x32_bf16(a1, bh0, acc[1][n], 0, 0, 0);
          acc[0][n] = __builtin_amdgcn_mfma_f32_16x16x32_bf16(a0, br0, acc[0][n], 0, 0, 0);
          acc[1][n] = __builtin_amdgcn_mfma_f32_16x16x32_bf16(a1, br0, acc[1][n], 0, 0, 0);
        }
      }
    }
  }

  // epilogue: C/D layout col=lane&15, row=(lane>>4)*4+reg
  int lrow = l & 15;
  int crow0 = (l >> 4) * 4;
  #pragma unroll
  for (int m = 0; m < 2; ++m) {
    long long vbase = (rtBase + m) * 16 + crow0;
    #pragma unroll
    for (int rr = 0; rr < 4; ++rr) {
      long long v = vbase + rr;
      if (v < N) {
        float* op = out + v * D + wc * 64 + lrow;
        #pragma unroll
        for (int n = 0; n < 4; ++n) op[n * 16] = tanhf(acc[m][n][rr]);
      }
    }
  }
}

extern "C" void kernel_launch(void* const* d_in, const int* in_sizes, int n_in,
                              void* d_out, int out_size, void* d_ws, size_t ws_size,
                              hipStream_t stream) {
  const float* x    = (const float*)d_in[0];
  const float* W    = (const float*)d_in[1];
  const int*   u    = (const int*)d_in[2];
  const int*   v    = (const int*)d_in[3];
  const int*   widx = (const int*)d_in[4];

  long long N  = (long long)in_sizes[0] / D;
  int       NW = in_sizes[1] / (D * D);
  long long E  = (long long)in_sizes[2];
  float* out = (float*)d_out;

  long long NB2 = (long long)NW * N;                // 800000
  int gemmBlocks = (int)((N + 63) / 64);            // 1563
  long long NpadA = (long long)gemmBlocks * 64;     // 100032
  long long nt16 = NpadA / 16;                      // 6252
  int nScanBlk = (int)((NB2 + 4095) / 4096);        // 196 (<=256 required)
  long long xTotal = N * D;

  // workspace layout
  char* ws = (char*)d_ws;
  int* cnt2    = (int*)ws;                        ws += (size_t)NB2 * sizeof(int);
  int* starts2 = (int*)ws;                        ws += ((size_t)NB2 + 1) * sizeof(int);
  int* cursor2 = (int*)ws;                        ws += (size_t)NB2 * sizeof(int);
  int* blkSums = (int*)ws;                        ws += 256 * sizeof(int);
  int* blkOff  = (int*)ws;                        ws += 256 * sizeof(int);
  int* sortedU = (int*)ws;                        ws += (size_t)E * sizeof(int);
  ws = (char*)(((uintptr_t)ws + 255) & ~(uintptr_t)255);
  unsigned short* Wp = (unsigned short*)ws;       ws += (size_t)NW * 32768 * 2;
  ws = (char*)(((uintptr_t)ws + 255) & ~(uintptr_t)255);
  unsigned short* xbf = (unsigned short*)ws;      ws += (size_t)xTotal * 2;
  ws = (char*)(((uintptr_t)ws + 255) & ~(uintptr_t)255);
  unsigned short* Sp = (unsigned short*)ws;       ws += (size_t)NW * NpadA * D * 2;
  (void)ws_size;

  dim3 blk(256);
  int edgeGrid = (int)((E + 255) / 256);
  int wpGrid = (NW * 2048 + 255) / 256;
  int xcGrid = (int)((xTotal / 8 + 255) / 256);

  hipMemsetAsync(cnt2, 0, (size_t)NB2 * sizeof(int), stream);
  hist_kernel<<<edgeGrid, blk, 0, stream>>>(v, widx, cnt2, E, N);
  scanA_kernel<<<nScanBlk, 1024, 0, stream>>>(cnt2, starts2, blkSums, NB2);
  scanB_kernel<<<1, 256, 0, stream>>>(blkSums, blkOff, nScanBlk);
  scanC_kernel<<<nScanBlk, 1024, 0, stream>>>(starts2, cursor2, blkOff, NB2,
                                              (int)E);
  scatter_ids_kernel<<<edgeGrid, blk, 0, stream>>>(u, v, widx, cursor2, sortedU,
                                                   E, N);
  xconv_kernel<<<xcGrid, blk, 0, stream>>>(x, xbf, xTotal);
  wconv_pack_kernel<<<wpGrid, blk, 0, stream>>>(W, Wp, NW);
  dim3 ggrid((unsigned)nt16, (unsigned)NW);
  gather_pack_kernel<<<ggrid, blk, 0, stream>>>(xbf, starts2, sortedU, Sp, N, nt16);
  if (NW == 8) {
    mfma_gemm_kernel<8><<<gemmBlocks, blk, 0, stream>>>(
        Sp, Wp, out, N, nt16, NW);
  } else {
    mfma_gemm_kernel<0><<<gemmBlocks, blk, 0, stream>>>(
        Sp, Wp, out, N, nt16, NW);
  }
}